// Round 22
// baseline (1441.675 us; speedup 1.0000x reference)
//
#include <hip/hip_runtime.h>

#define TPB 256
#define KNN_TPB 512
static inline int nblk(long n) { return (int)((n + TPB - 1) / TPB); }

#define FINF 3.402823466e38f

// ---------------- KNN body: radix-select + fused epilogues (K=20 fixed) ----------------
template <int NS, bool WDIR, bool CSURF, int K2>
__device__ __forceinline__ void knn_body(int bx, int b, const float* __restrict__ vin,
                                         int* __restrict__ knn, float* __restrict__ ndir,
                                         int V_out, const float* __restrict__ c0dir,
                                         float* __restrict__ fm0, int V2, int* __restrict__ knn4,
                                         float4* pts, int (*sidx)[20], float (*sdir)[20][3],
                                         unsigned (*cdist)[256], unsigned short (*cidx)[256]) {
    constexpr int K = 20;
    constexpr int VF = NS * 64;
    const float* vb = vin + (size_t)b * 3072; // (3, 1024) layout
    for (int j = threadIdx.x; j < VF; j += blockDim.x) {
        float x = vb[j], y = vb[1024 + j], z = vb[2048 + j];
        pts[j] = make_float4(x, y, z, x * x + y * y + z * z);
    }
    __syncthreads();
    int lane = threadIdx.x & 63;
    int w = threadIdx.x >> 6;
    int i = bx * 8 + w;
    if (i >= V_out) return;
    float4 pi = pts[i];
    unsigned ud[NS];
    unsigned lmin = 0xFFFFFFFFu;
#pragma unroll
    for (int s = 0; s < NS; ++s) {
        int j = s * 64 + lane;
        float4 pj = pts[j];
        float dist = pi.w + pj.w - 2.f * (pi.x * pj.x + pi.y * pj.y + pi.z * pj.z);
        dist = fmaxf(dist, 0.f);
        unsigned v = (j == i) ? 0xFFFFFFFFu : __float_as_uint(dist);
        ud[s] = v;
        lmin = v < lmin ? v : lmin;
    }
    unsigned pmin = lmin;
    {
        unsigned o = (unsigned)__shfl_xor((int)pmin, 1, 64);
        pmin = o < pmin ? o : pmin;
    }
    unsigned gmin = lmin, M = pmin;
#pragma unroll
    for (int off = 32; off > 1; off >>= 1) {
        unsigned on = (unsigned)__shfl_xor((int)gmin, off, 64);
        gmin = on < gmin ? on : gmin;
        unsigned om = (unsigned)__shfl_xor((int)M, off, 64);
        M = om > M ? om : M;
    }
    {
        unsigned on = (unsigned)__shfl_xor((int)gmin, 1, 64);
        gmin = on < gmin ? on : gmin;
    }
    int* orow = knn + ((size_t)(b * V_out + i)) * K;
    unsigned long long lmask = (1ull << lane) - 1ull;
    bool done = false;
    if constexpr (NS >= 8) {
        int cnt = 0;
#pragma unroll
        for (int s = 0; s < NS; ++s) {
            unsigned long long mm = __ballot(ud[s] <= M);
            if (ud[s] <= M) {
                int p = cnt + __popcll(mm & lmask);
                if (p < 256) { cdist[w][p] = ud[s]; cidx[w][p] = (unsigned short)(s * 64 + lane); }
            }
            cnt += __popcll(mm);
        }
        if (cnt <= 256) {
            unsigned cd[4];
#pragma unroll
            for (int r = 0; r < 4; ++r) {
                int p = lane + r * 64;
                cd[r] = p < cnt ? cdist[w][p] : 0xFFFFFFFFu;
            }
            unsigned lo = gmin, hi = M + 1u;
            while (hi - lo > 1u) {
                unsigned mid = lo + ((hi - lo) >> 1);
                int c = 0;
#pragma unroll
                for (int r = 0; r < 4; ++r)
                    c += __popcll(__ballot(cd[r] < mid));
                if (c >= K) hi = mid; else lo = mid;
            }
            unsigned T = lo;
            int base = 0;
#pragma unroll
            for (int r = 0; r < 4; ++r) {
                unsigned long long mm = __ballot(cd[r] < T);
                if (cd[r] < T) {
                    int p = base + __popcll(mm & lmask);
                    int j = cidx[w][lane + r * 64];
                    sidx[w][p] = j; orow[p] = j;
                }
                base += __popcll(mm);
            }
            int need = K - base, run = 0;
#pragma unroll
            for (int r = 0; r < 4; ++r) {
                unsigned long long mm = __ballot(cd[r] == T);
                int rr = run + __popcll(mm & lmask);
                if (cd[r] == T && rr < need) {
                    int j = cidx[w][lane + r * 64];
                    sidx[w][base + rr] = j; orow[base + rr] = j;
                }
                run += __popcll(mm);
            }
            done = true;
        }
    }
    if (!done) {
        unsigned lo = gmin, hi = M + 1u;
        while (hi - lo > 1u) {
            unsigned mid = lo + ((hi - lo) >> 1);
            int cnt = 0;
#pragma unroll
            for (int s = 0; s < NS; ++s)
                cnt += __popcll(__ballot(ud[s] < mid));
            if (cnt >= K) hi = mid; else lo = mid;
        }
        unsigned T = lo;
        int base = 0;
#pragma unroll
        for (int s = 0; s < NS; ++s) {
            unsigned long long m = __ballot(ud[s] < T);
            if (ud[s] < T) {
                int p = base + __popcll(m & lmask);
                sidx[w][p] = s * 64 + lane;
                orow[p] = s * 64 + lane;
            }
            base += __popcll(m);
        }
        int need = K - base, run = 0;
#pragma unroll
        for (int s = 0; s < NS; ++s) {
            unsigned long long m = __ballot(ud[s] == T);
            int r = run + __popcll(m & lmask);
            if (ud[s] == T && r < need) {
                sidx[w][base + r] = s * 64 + lane;
                orow[base + r] = s * 64 + lane;
            }
            run += __popcll(m);
        }
    }
    if (WDIR) {
        if (lane < K) {
            int j = sidx[w][lane];
            float4 pj = pts[j];
            float dx = pj.x - pi.x, dy = pj.y - pi.y, dz = pj.z - pi.z;
            float inv = 1.f / fmaxf(sqrtf(dx * dx + dy * dy + dz * dz), 1e-12f);
            float* o = ndir + ((size_t)(b * V_out + i) * K + lane) * 3;
            float nx = dx * inv, ny = dy * inv, nz = dz * inv;
            o[0] = nx; o[1] = ny; o[2] = nz;
            if (CSURF) { sdir[w][lane][0] = nx; sdir[w][lane][1] = ny; sdir[w][lane][2] = nz; }
        }
        if (CSURF && lane < 32) {
            int c = lane;
            float d0 = c0dir[c], d1 = c0dir[32 + c], d2 = c0dir[64 + c];
            float inv = 1.f / fmaxf(sqrtf(d0 * d0 + d1 * d1 + d2 * d2), 1e-12f);
            d0 *= inv; d1 *= inv; d2 *= inv;
            float m = 0.f;
            for (int n = 0; n < K; ++n) {
                float th = sdir[w][n][0] * d0 + sdir[w][n][1] * d1 + sdir[w][n][2] * d2;
                m = fmaxf(m, th);
            }
            fm0[(size_t)(b * V_out + i) * 32 + c] = m;
        }
    }
    if (K2 > 0 && i < V2) {
        float dsel = FINF;
        int jsel = 0x7FFFFFFF;
        if (lane < K) {
            jsel = sidx[w][lane];
            float4 pj = pts[jsel];
            dsel = fmaxf(pi.w + pj.w - 2.f * (pi.x * pj.x + pi.y * pj.y + pi.z * pj.z), 0.f);
        }
        int rank = 0;
        for (int m = 0; m < K; ++m) {
            float dm = __shfl(dsel, m, 64);
            int jm = __shfl(jsel, m, 64);
            rank += (dm < dsel || (dm == dsel && jm < jsel)) ? 1 : 0;
        }
        if (lane < K && rank < K2) knn4[((size_t)(b * V2 + i)) * K2 + rank] = jsel;
    }
}

// ---------------- prep (1-D grid): knn stages + transposes + BN-bin/barrier zeroing ----------------
// bx < 5376: knn work (b = bx/168, r = bx%168: r<128 knn1, r<160 knn2, else knn3).
// bx >= 5376: linear chain of transposes (305152 threads) then zeroing (57408).
__global__ __launch_bounds__(KNN_TPB, 1) void prep_kernel(const float* __restrict__ vin, const float* __restrict__ c0dir,
                                                          int* __restrict__ knn1, float* __restrict__ ndir1,
                                                          float* __restrict__ fm0, int* __restrict__ knn4_1,
                                                          int* __restrict__ knn2, float* __restrict__ ndir2,
                                                          int* __restrict__ knn4_2,
                                                          int* __restrict__ knn3, float* __restrict__ ndir3,
                                                          const float* __restrict__ d1, const float* __restrict__ d2,
                                                          const float* __restrict__ d3, const float* __restrict__ d4,
                                                          float* __restrict__ o1, float* __restrict__ o2,
                                                          float* __restrict__ o3, float* __restrict__ o4,
                                                          float* __restrict__ pz) {
    __shared__ float4 pts[1024];
    __shared__ int sidx[8][20];
    __shared__ float sdir[8][20][3];
    __shared__ unsigned cdist[8][256];
    __shared__ unsigned short cidx[8][256];
    int bx = blockIdx.x;
    if (bx < 5376) {
        int b = bx / 168;
        int r = bx - b * 168;
        if (r < 128) {
            knn_body<16, true, true, 4>(r, b, vin, knn1, ndir1, 1024, c0dir, fm0, 256, knn4_1,
                                        pts, sidx, sdir, cdist, cidx);
        } else if (r < 160) {
            knn_body<4, true, false, 4>(r - 128, b, vin, knn2, ndir2, 256, nullptr, nullptr, 64, knn4_2,
                                        pts, sidx, sdir, cdist, cidx);
        } else {
            knn_body<1, true, false, 0>(r - 160, b, vin, knn3, ndir3, 64, nullptr, nullptr, 0, nullptr,
                                        pts, sidx, sdir, cdist, cidx);
        }
        return;
    }
    int t = (bx - 5376) * KNN_TPB + threadIdx.x;
    if (t < 2048) { int r = t / 32, c = t % 32; o1[c * 64 + r] = d1[t]; return; }
    int t2 = t - 2048;
    if (t2 < 8192) { int r = t2 / 64, c = t2 % 64; o2[c * 128 + r] = d2[t2]; return; }
    int t3 = t2 - 8192;
    if (t3 < 32768) { int r = t3 / 128, c = t3 % 128; o3[c * 256 + r] = d3[t3]; return; }
    int t4 = t3 - 32768;
    if (t4 < 262144) { int r = t4 / 256, c = t4 % 256; o4[c * 1024 + r] = d4[t4]; return; }
    int t5 = t4 - 262144;
    if (t5 < 57408) pz[t5] = 0.f; // BN bins (57344) + barrier cells (64 ints)
}

// ---------------- device-scope grid barrier (cells zeroed by prep each launch) ----------------
__device__ __forceinline__ void grid_bar(int* cells, int site, int nb) {
    __syncthreads();
    if (threadIdx.x == 0) {
        __threadfence();
        int* cnt = cells + site * 2;
        int* flg = cnt + 1;
        if (atomicAdd(cnt, 1) == nb - 1) {
            atomicExch(flg, 1);
        } else {
            while (atomicAdd(flg, 0) == 0) { __builtin_amdgcn_s_sleep(2); }
        }
        __threadfence();
    }
    __syncthreads();
}

// ---------------- GEMM body (smem arena 22784 B): 64x64 tile, BK=32 ----------------
// MODE 0: +bias.  MODE 1: bnrelu(conv)+A@W (parallel BN finalize).  MODE 2: +col-max -> gbuf.
template <int MODE>
__device__ void gemm64_body(char* smem, int bx, int by,
                            const float* __restrict__ A, const float* __restrict__ W,
                            const float* __restrict__ bias,
                            const float* __restrict__ conv, const float* __restrict__ partial,
                            float* __restrict__ out, int M, int N, int K, int nsplit) {
    float (*As)[36] = (float(*)[36])smem;                 // 9216 B
    float (*Bs)[68] = (float(*)[68])(smem + 9216);        // 8704 B -> 17920
    float* smean = (float*)(smem + 17920);                // 256 B
    float* sinv  = (float*)(smem + 18176);                // 256 B
    int t = threadIdx.x;
    int tx = t & 15, ty = t >> 4;
    int colbase = bx * 64, rowbase = by * 64;
    int r0 = ty * 4, c0 = tx * 4;
    if constexpr (MODE >= 1) {
        double (*sred)[4][64] = (double(*)[4][64])(smem + 18432); // 4096 B
        int cc = t & 63, gq = t >> 6;
        double s = 0.0, ss = 0.0;
        for (int sp = gq; sp < nsplit; sp += 4) {
            s += partial[(size_t)sp * 2 * N + colbase + cc];
            ss += partial[(size_t)sp * 2 * N + N + colbase + cc];
        }
        sred[0][gq][cc] = s; sred[1][gq][cc] = ss;
        __syncthreads();
        if (t < 64) {
            double S = sred[0][0][t] + sred[0][1][t] + sred[0][2][t] + sred[0][3][t];
            double SS = sred[1][0][t] + sred[1][1][t] + sred[1][2][t] + sred[1][3][t];
            double mean = S / M;
            double var = SS / M - mean * mean;
            if (var < 0) var = 0;
            smean[t] = (float)mean;
            sinv[t] = rsqrtf((float)var + 1e-5f);
        }
        __syncthreads();
    }
    float4 acc0, acc1, acc2, acc3;
    if (MODE == 0) {
        float4 bv = *(const float4*)(bias + colbase + c0);
        acc0 = bv; acc1 = bv; acc2 = bv; acc3 = bv;
    } else {
        acc0 = make_float4(0.f, 0.f, 0.f, 0.f); acc1 = acc0; acc2 = acc0; acc3 = acc0;
    }
    for (int kt = 0; kt < K; kt += 32) {
#pragma unroll
        for (int l = 0; l < 2; ++l) {
            int lin = t + l * 256;
            int ar = lin >> 3, ak = (lin & 7) << 2;
            *(float4*)&As[ar][ak] = *(const float4*)(A + (size_t)(rowbase + ar) * K + kt + ak);
            int br = lin >> 4, bn = (lin & 15) << 2;
            *(float4*)&Bs[br][bn] = *(const float4*)(W + (size_t)(kt + br) * N + colbase + bn);
        }
        __syncthreads();
#pragma unroll 4
        for (int k = 0; k < 32; ++k) {
            float4 bv = *(const float4*)&Bs[k][c0];
            float a0 = As[r0][k], a1 = As[r0 + 1][k], a2 = As[r0 + 2][k], a3 = As[r0 + 3][k];
            acc0.x += a0 * bv.x; acc0.y += a0 * bv.y; acc0.z += a0 * bv.z; acc0.w += a0 * bv.w;
            acc1.x += a1 * bv.x; acc1.y += a1 * bv.y; acc1.z += a1 * bv.z; acc1.w += a1 * bv.w;
            acc2.x += a2 * bv.x; acc2.y += a2 * bv.y; acc2.z += a2 * bv.z; acc2.w += a2 * bv.w;
            acc3.x += a3 * bv.x; acc3.y += a3 * bv.y; acc3.z += a3 * bv.z; acc3.w += a3 * bv.w;
        }
        __syncthreads();
    }
    float4 accs[4] = {acc0, acc1, acc2, acc3};
    if constexpr (MODE >= 1) {
        float4 mean = *(const float4*)&smean[c0];
        float4 inv = *(const float4*)&sinv[c0];
#pragma unroll
        for (int rr = 0; rr < 4; ++rr) {
            float4 cv = *(const float4*)(conv + (size_t)(rowbase + r0 + rr) * N + colbase + c0);
            accs[rr].x += fmaxf((cv.x - mean.x) * inv.x, 0.f);
            accs[rr].y += fmaxf((cv.y - mean.y) * inv.y, 0.f);
            accs[rr].z += fmaxf((cv.z - mean.z) * inv.z, 0.f);
            accs[rr].w += fmaxf((cv.w - mean.w) * inv.w, 0.f);
        }
    }
    if constexpr (MODE == 2) {
        float (*redmax)[68] = (float(*)[68])(smem + 18432); // 4352 B (overlays sred, disjoint in time)
        float4 tm;
        tm.x = fmaxf(fmaxf(accs[0].x, accs[1].x), fmaxf(accs[2].x, accs[3].x));
        tm.y = fmaxf(fmaxf(accs[0].y, accs[1].y), fmaxf(accs[2].y, accs[3].y));
        tm.z = fmaxf(fmaxf(accs[0].z, accs[1].z), fmaxf(accs[2].z, accs[3].z));
        tm.w = fmaxf(fmaxf(accs[0].w, accs[1].w), fmaxf(accs[2].w, accs[3].w));
        *(float4*)&redmax[ty][c0] = tm;
        __syncthreads();
        if (t < 64) {
            float m = redmax[0][t];
#pragma unroll
            for (int gq = 1; gq < 16; ++gq) m = fmaxf(m, redmax[gq][t]);
            out[(size_t)by * N + colbase + t] = m;
        }
    } else {
#pragma unroll
        for (int rr = 0; rr < 4; ++rr)
            *(float4*)(out + (size_t)(rowbase + r0 + rr) * N + colbase + c0) = accs[rr];
    }
}

// ---------------- conv_act body (arena: 2 KB) ----------------
template <bool FUSE>
__device__ void conv_act_body(char* smem, int tile, const float* __restrict__ ndir, const int* __restrict__ knn,
                              const float* __restrict__ fout, const float* __restrict__ dir,
                              float* __restrict__ out, int B, int Vst, int K, int Cout,
                              float* __restrict__ bnpart) {
    float (*sAcc)[256] = (float(*)[256])smem;
    int t = tile * TPB + threadIdx.x;
    int nc4 = Cout >> 2;
    bool active = t < B * Vst * nc4;
    float4 o = make_float4(0.f, 0.f, 0.f, 0.f);
    int c4 = 0;
    if (active) {
        int row = t / nc4; c4 = (t % nc4) * 4;
        int b = row / Vst;
        float4 D0 = *(const float4*)(dir + c4);
        float4 D1 = *(const float4*)(dir + Cout + c4);
        float4 D2 = *(const float4*)(dir + 2 * Cout + c4);
        float4 e0, e1, e2;
        {
            float i0 = 1.f / fmaxf(sqrtf(D0.x * D0.x + D1.x * D1.x + D2.x * D2.x), 1e-12f);
            float i1 = 1.f / fmaxf(sqrtf(D0.y * D0.y + D1.y * D1.y + D2.y * D2.y), 1e-12f);
            float i2 = 1.f / fmaxf(sqrtf(D0.z * D0.z + D1.z * D1.z + D2.z * D2.z), 1e-12f);
            float i3 = 1.f / fmaxf(sqrtf(D0.w * D0.w + D1.w * D1.w + D2.w * D2.w), 1e-12f);
            e0 = make_float4(D0.x * i0, D0.y * i1, D0.z * i2, D0.w * i3);
            e1 = make_float4(D1.x * i0, D1.y * i1, D1.z * i2, D1.w * i3);
            e2 = make_float4(D2.x * i0, D2.y * i1, D2.z * i2, D2.w * i3);
        }
        int Cw = 2 * Cout;
        float4 m = make_float4(-FINF, -FINF, -FINF, -FINF);
        const float* nd = ndir + (size_t)row * K * 3;
        const int* kr = knn + (size_t)row * K;
        for (int n = 0; n < K; ++n) {
            int j = kr[n];
            float n0 = nd[n * 3], n1 = nd[n * 3 + 1], n2 = nd[n * 3 + 2];
            float4 s = *(const float4*)(fout + ((size_t)(b * Vst + j)) * Cw + Cout + c4);
            float t0 = fmaxf(n0 * e0.x + n1 * e1.x + n2 * e2.x, 0.f);
            float t1 = fmaxf(n0 * e0.y + n1 * e1.y + n2 * e2.y, 0.f);
            float t2 = fmaxf(n0 * e0.z + n1 * e1.z + n2 * e2.z, 0.f);
            float t3 = fmaxf(n0 * e0.w + n1 * e1.w + n2 * e2.w, 0.f);
            m.x = fmaxf(m.x, t0 * s.x);
            m.y = fmaxf(m.y, t1 * s.y);
            m.z = fmaxf(m.z, t2 * s.z);
            m.w = fmaxf(m.w, t3 * s.w);
        }
        float4 ctr = *(const float4*)(fout + (size_t)row * Cw + c4);
        o = make_float4(ctr.x + m.x, ctr.y + m.y, ctr.z + m.z, ctr.w + m.w);
        *(float4*)(out + (size_t)row * Cout + c4) = o;
    }
    if constexpr (FUSE) {
        for (int i = threadIdx.x; i < 2 * Cout; i += TPB) ((float*)sAcc)[i < Cout ? i : 256 + (i - Cout)] = 0.f;
        __syncthreads();
        if (active) {
            atomicAdd(&sAcc[0][c4 + 0], o.x); atomicAdd(&sAcc[1][c4 + 0], o.x * o.x);
            atomicAdd(&sAcc[0][c4 + 1], o.y); atomicAdd(&sAcc[1][c4 + 1], o.y * o.y);
            atomicAdd(&sAcc[0][c4 + 2], o.z); atomicAdd(&sAcc[1][c4 + 2], o.z * o.z);
            atomicAdd(&sAcc[0][c4 + 3], o.w); atomicAdd(&sAcc[1][c4 + 3], o.w * o.w);
        }
        __syncthreads();
        int bin = tile & 63;
        for (int i = threadIdx.x; i < Cout; i += TPB) {
            atomicAdd(&bnpart[(size_t)bin * 2 * Cout + i], sAcc[0][i]);
            atomicAdd(&bnpart[(size_t)bin * 2 * Cout + Cout + i], sAcc[1][i]);
        }
    }
}

// ---------------- pool body ----------------
__device__ void pool_max_body(int tile, const float* __restrict__ fm, const int* __restrict__ knn4,
                              float* __restrict__ out, int B, int Vin, int pn, int C) {
    int t = tile * TPB + threadIdx.x;
    if (t >= B * pn * C) return;
    int row = t / C, c = t % C;
    int b = row / pn;
    const int* kr = knn4 + (size_t)row * 4;
    float m = fmaxf(fmaxf(fm[((size_t)(b * Vin + kr[0])) * C + c], fm[((size_t)(b * Vin + kr[1])) * C + c]),
                    fmaxf(fm[((size_t)(b * Vin + kr[2])) * C + c], fm[((size_t)(b * Vin + kr[3])) * C + c]));
    out[t] = m;
}

// ---------------- wave-per-output classifier GEMM body ----------------
__device__ void gemm_t_wave_body(int tile, const float* __restrict__ in, const float* __restrict__ w,
                                 const float* __restrict__ bias, float* __restrict__ out,
                                 int rows, int Cin, int Cout) {
    int wid = (tile * TPB + threadIdx.x) >> 6;
    int lane = threadIdx.x & 63;
    if (wid >= rows * Cout) return;
    int r = wid / Cout, c = wid % Cout;
    const float4* a = (const float4*)(in + (size_t)r * Cin);
    const float4* wr = (const float4*)(w + (size_t)c * Cin);
    int n4 = Cin >> 2;
    float acc = 0.f;
    for (int k = lane; k < n4; k += 64) {
        float4 av = a[k], wv = wr[k];
        acc += av.x * wv.x + av.y * wv.y + av.z * wv.z + av.w * wv.w;
    }
#pragma unroll
    for (int off = 32; off > 0; off >>= 1) acc += __shfl_xor(acc, off, 64);
    if (lane == 0) out[wid] = acc + bias[c];
}

// ---------------- classifier tail body (arena: 2 KB) ----------------
__device__ void cls_fused_body(char* smem, int tile, const float* __restrict__ h,
                               const float* __restrict__ gam, const float* __restrict__ beta,
                               const float* __restrict__ w2, const float* __restrict__ b2,
                               float* __restrict__ out) {
    float* smean = (float*)smem;
    float* sa = smean + 256;
    int t = threadIdx.x;
    {
        float s = 0.f, ss = 0.f;
        for (int b = 0; b < 32; ++b) {
            float v = h[(size_t)b * 256 + t];
            s += v; ss += v * v;
        }
        float mn = s / 32.f;
        float var = ss / 32.f - mn * mn;
        if (var < 0.f) var = 0.f;
        smean[t] = mn;
        sa[t] = rsqrtf(var + 1e-5f) * gam[t];
    }
    __syncthreads();
    int wid = tile * 4 + (t >> 6);
    int lane = t & 63;
    if (wid >= 32 * 40) return;
    int b = wid / 40, o = wid % 40;
    float acc = 0.f;
#pragma unroll
    for (int kk = 0; kk < 4; ++kk) {
        int c = lane + kk * 64;
        float v = fmaxf((h[b * 256 + c] - smean[c]) * sa[c] + beta[c], 0.f);
        acc += v * w2[o * 256 + c];
    }
#pragma unroll
    for (int off = 32; off > 0; off >>= 1) acc += __shfl_xor(acc, off, 64);
    if (lane == 0) out[wid] = acc + b2[o];
}

// ---------------- stage-3 FUSED (standalone; 52.7 KB LDS, kept out of megas) ----------------
__global__ __launch_bounds__(TPB) void s3_fused_kernel(const float* __restrict__ A, const float* __restrict__ W,
                                                       const float* __restrict__ bias,
                                                       const float* __restrict__ ndir, const int* __restrict__ knn,
                                                       const float* __restrict__ dir,
                                                       float* __restrict__ convp, float* __restrict__ bnpart) {
    constexpr int K = 256, N = 2048, Cout = 1024, KN = 20;
    __shared__ float As[64][36];
    __shared__ float Bc[32][68];
    __shared__ float Bsup[32][68];
    __shared__ float S[64][68];
    __shared__ float red[2][16][68];
    int t = threadIdx.x;
    int tx = t & 15, ty = t >> 4;
    int r0 = ty * 4, c0 = tx * 4;
    int batch = blockIdx.y;
    int colbase = blockIdx.x * 64;
    int rowbase = batch * 64;
    float4 accC[4], accS[4];
    {
        float4 bc = *(const float4*)(bias + colbase + c0);
        float4 bs = *(const float4*)(bias + Cout + colbase + c0);
#pragma unroll
        for (int rr = 0; rr < 4; ++rr) { accC[rr] = bc; accS[rr] = bs; }
    }
    for (int kt = 0; kt < K; kt += 32) {
#pragma unroll
        for (int l = 0; l < 2; ++l) {
            int lin = t + l * 256;
            int ar = lin >> 3, ak = (lin & 7) << 2;
            *(float4*)&As[ar][ak] = *(const float4*)(A + (size_t)(rowbase + ar) * K + kt + ak);
            int br = lin >> 4, bn = (lin & 15) << 2;
            *(float4*)&Bc[br][bn] = *(const float4*)(W + (size_t)(kt + br) * N + colbase + bn);
            *(float4*)&Bsup[br][bn] = *(const float4*)(W + (size_t)(kt + br) * N + Cout + colbase + bn);
        }
        __syncthreads();
#pragma unroll 4
        for (int k = 0; k < 32; ++k) {
            float4 bc = *(const float4*)&Bc[k][c0];
            float4 bs = *(const float4*)&Bsup[k][c0];
            float a0 = As[r0][k], a1 = As[r0 + 1][k], a2 = As[r0 + 2][k], a3 = As[r0 + 3][k];
            accC[0].x += a0 * bc.x; accC[0].y += a0 * bc.y; accC[0].z += a0 * bc.z; accC[0].w += a0 * bc.w;
            accC[1].x += a1 * bc.x; accC[1].y += a1 * bc.y; accC[1].z += a1 * bc.z; accC[1].w += a1 * bc.w;
            accC[2].x += a2 * bc.x; accC[2].y += a2 * bc.y; accC[2].z += a2 * bc.z; accC[2].w += a2 * bc.w;
            accC[3].x += a3 * bc.x; accC[3].y += a3 * bc.y; accC[3].z += a3 * bc.z; accC[3].w += a3 * bc.w;
            accS[0].x += a0 * bs.x; accS[0].y += a0 * bs.y; accS[0].z += a0 * bs.z; accS[0].w += a0 * bs.w;
            accS[1].x += a1 * bs.x; accS[1].y += a1 * bs.y; accS[1].z += a1 * bs.z; accS[1].w += a1 * bs.w;
            accS[2].x += a2 * bs.x; accS[2].y += a2 * bs.y; accS[2].z += a2 * bs.z; accS[2].w += a2 * bs.w;
            accS[3].x += a3 * bs.x; accS[3].y += a3 * bs.y; accS[3].z += a3 * bs.z; accS[3].w += a3 * bs.w;
        }
        __syncthreads();
    }
#pragma unroll
    for (int rr = 0; rr < 4; ++rr)
        *(float4*)&S[r0 + rr][c0] = accS[rr];
    __syncthreads();
    int c = colbase + c0;
    float4 D0 = *(const float4*)(dir + c);
    float4 D1 = *(const float4*)(dir + Cout + c);
    float4 D2 = *(const float4*)(dir + 2 * Cout + c);
    float4 e0, e1, e2;
    {
        float i0 = 1.f / fmaxf(sqrtf(D0.x * D0.x + D1.x * D1.x + D2.x * D2.x), 1e-12f);
        float i1 = 1.f / fmaxf(sqrtf(D0.y * D0.y + D1.y * D1.y + D2.y * D2.y), 1e-12f);
        float i2 = 1.f / fmaxf(sqrtf(D0.z * D0.z + D1.z * D1.z + D2.z * D2.z), 1e-12f);
        float i3 = 1.f / fmaxf(sqrtf(D0.w * D0.w + D1.w * D1.w + D2.w * D2.w), 1e-12f);
        e0 = make_float4(D0.x * i0, D0.y * i1, D0.z * i2, D0.w * i3);
        e1 = make_float4(D1.x * i0, D1.y * i1, D1.z * i2, D1.w * i3);
        e2 = make_float4(D2.x * i0, D2.y * i1, D2.z * i2, D2.w * i3);
    }
    float4 sum = make_float4(0.f, 0.f, 0.f, 0.f);
    float4 ssum = make_float4(0.f, 0.f, 0.f, 0.f);
#pragma unroll
    for (int rr = 0; rr < 4; ++rr) {
        int row = rowbase + r0 + rr;
        float4 m = make_float4(-FINF, -FINF, -FINF, -FINF);
        const float* nd = ndir + (size_t)row * KN * 3;
        const int* kr = knn + (size_t)row * KN;
        for (int n = 0; n < KN; ++n) {
            int j = kr[n];
            float n0 = nd[n * 3], n1 = nd[n * 3 + 1], n2 = nd[n * 3 + 2];
            float4 s = *(const float4*)&S[j][c0];
            float t0 = fmaxf(n0 * e0.x + n1 * e1.x + n2 * e2.x, 0.f);
            float t1 = fmaxf(n0 * e0.y + n1 * e1.y + n2 * e2.y, 0.f);
            float t2 = fmaxf(n0 * e0.z + n1 * e1.z + n2 * e2.z, 0.f);
            float t3 = fmaxf(n0 * e0.w + n1 * e1.w + n2 * e2.w, 0.f);
            m.x = fmaxf(m.x, t0 * s.x);
            m.y = fmaxf(m.y, t1 * s.y);
            m.z = fmaxf(m.z, t2 * s.z);
            m.w = fmaxf(m.w, t3 * s.w);
        }
        float4 o = make_float4(accC[rr].x + m.x, accC[rr].y + m.y, accC[rr].z + m.z, accC[rr].w + m.w);
        *(float4*)(convp + (size_t)row * Cout + colbase + c0) = o;
        sum.x += o.x; sum.y += o.y; sum.z += o.z; sum.w += o.w;
        ssum.x += o.x * o.x; ssum.y += o.y * o.y; ssum.z += o.z * o.z; ssum.w += o.w * o.w;
    }
    *(float4*)&red[0][ty][c0] = sum;
    *(float4*)&red[1][ty][c0] = ssum;
    __syncthreads();
    if (t < 64) {
        float Ssum = 0.f, SSsum = 0.f;
#pragma unroll
        for (int gq = 0; gq < 16; ++gq) { Ssum += red[0][gq][t]; SSsum += red[1][gq][t]; }
        bnpart[(size_t)batch * 2048 + colbase + t] = Ssum;
        bnpart[(size_t)batch * 2048 + 1024 + colbase + t] = SSsum;
    }
}

// ---------------- mega-kernels with manual grid barriers ----------------
struct NetArgs {
    const float *c1_w, *c1_b, *c1_dir, *c2_w, *c2_b, *c2_dir, *c3_w, *c3_b, *c3_dir;
    const float *cls_w1, *cls_b1, *cls_g, *cls_beta, *cls_w2, *cls_b2;
    const int *knn1, *knn2, *knn4_1, *knn4_2;
    const float *ndir1, *ndir2;
    float *fm0, *fm1, *fm1p, *fm2, *fm3, *fm3p, *fout, *convp, *gbuf, *hbuf;
    float *d1t, *d2t, *d3t, *p1, *p2a, *p2b, *d4t, *p3;
    float *outp;
    int *bar;
};

__global__ __launch_bounds__(TPB, 4) void mega1_kernel(NetArgs a) {
    __shared__ alignas(16) char smem[22784];
    int nb = gridDim.x;
    int* bar = a.bar;
    for (int t = blockIdx.x; t < 1024; t += nb) { __syncthreads(); gemm64_body<0>(smem, t & 1, t >> 1, a.fm0, a.c1_w, a.c1_b, nullptr, nullptr, a.fout, 32768, 128, 32, 0); }
    grid_bar(bar, 0, nb);
    for (int t = blockIdx.x; t < 2048; t += nb) { __syncthreads(); conv_act_body<true>(smem, t, a.ndir1, a.knn1, a.fout, a.c1_dir, a.convp, 32, 1024, 20, 64, a.p1); }
    grid_bar(bar, 1, nb);
    for (int t = blockIdx.x; t < 512; t += nb) { __syncthreads(); gemm64_body<1>(smem, 0, t, a.fm0, a.d1t, nullptr, a.convp, a.p1, a.fm1, 32768, 64, 32, 64); }
    grid_bar(bar, 2, nb);
    for (int t = blockIdx.x; t < 2048; t += nb) pool_max_body(t, a.fm1, a.knn4_1, a.fm1p, 32, 1024, 256, 64);
    grid_bar(bar, 3, nb);
    for (int t = blockIdx.x; t < 512; t += nb) { __syncthreads(); gemm64_body<0>(smem, t & 3, t >> 2, a.fm1p, a.c2_w, a.c2_b, nullptr, nullptr, a.fout, 8192, 256, 64, 0); }
    grid_bar(bar, 4, nb);
    for (int t = blockIdx.x; t < 1024; t += nb) { __syncthreads(); conv_act_body<true>(smem, t, a.ndir2, a.knn2, a.fout, a.c2_dir, a.convp, 32, 256, 20, 128, a.p2a); }
    grid_bar(bar, 5, nb);
    for (int t = blockIdx.x; t < 256; t += nb) { __syncthreads(); gemm64_body<1>(smem, t & 1, t >> 1, a.fm1p, a.d2t, nullptr, a.convp, a.p2a, a.fm2, 8192, 128, 64, 64); }
    grid_bar(bar, 6, nb);
    for (int t = blockIdx.x; t < 1024; t += nb) { __syncthreads(); gemm64_body<0>(smem, t & 7, t >> 3, a.fm2, a.c3_w, a.c3_b, nullptr, nullptr, a.fout, 8192, 512, 128, 0); }
    grid_bar(bar, 7, nb);
    for (int t = blockIdx.x; t < 2048; t += nb) { __syncthreads(); conv_act_body<true>(smem, t, a.ndir2, a.knn2, a.fout, a.c3_dir, a.convp, 32, 256, 20, 256, a.p2b); }
    grid_bar(bar, 8, nb);
    for (int t = blockIdx.x; t < 512; t += nb) { __syncthreads(); gemm64_body<1>(smem, t & 3, t >> 2, a.fm2, a.d3t, nullptr, a.convp, a.p2b, a.fm3, 8192, 256, 128, 64); }
    grid_bar(bar, 9, nb);
    for (int t = blockIdx.x; t < 2048; t += nb) pool_max_body(t, a.fm3, a.knn4_2, a.fm3p, 32, 256, 64, 256);
}

__global__ __launch_bounds__(TPB, 4) void mega2_kernel(NetArgs a) {
    __shared__ alignas(16) char smem[22784];
    int nb = gridDim.x;
    int* bar = a.bar;
    for (int t = blockIdx.x; t < 512; t += nb) { __syncthreads(); gemm64_body<2>(smem, t & 15, t >> 4, a.fm3p, a.d4t, nullptr, a.convp, a.p3, a.gbuf, 2048, 1024, 256, 32); }
    grid_bar(bar, 10, nb);
    for (int t = blockIdx.x; t < 2048; t += nb) gemm_t_wave_body(t, a.gbuf, a.cls_w1, a.cls_b1, a.hbuf, 32, 1024, 256);
    grid_bar(bar, 11, nb);
    for (int t = blockIdx.x; t < 320; t += nb) { __syncthreads(); cls_fused_body(smem, t, a.hbuf, a.cls_g, a.cls_beta, a.cls_w2, a.cls_b2, a.outp); }
}

extern "C" void kernel_launch(void* const* d_in, const int* in_sizes, int n_in,
                              void* d_out, int out_size, void* d_ws, size_t ws_size,
                              hipStream_t stream) {
    const float* vertices = (const float*)d_in[0];
    const float* c0_dir = (const float*)d_in[1];
    const float* c1_w  = (const float*)d_in[2];
    const float* c1_b  = (const float*)d_in[3];
    const float* c1_dir = (const float*)d_in[4];
    const float* d1_w  = (const float*)d_in[5];
    const float* c2_w  = (const float*)d_in[6];
    const float* c2_b  = (const float*)d_in[7];
    const float* c2_dir = (const float*)d_in[8];
    const float* d2_w  = (const float*)d_in[9];
    const float* c3_w  = (const float*)d_in[10];
    const float* c3_b  = (const float*)d_in[11];
    const float* c3_dir = (const float*)d_in[12];
    const float* d3_w  = (const float*)d_in[13];
    const float* c4_w  = (const float*)d_in[14];
    const float* c4_b  = (const float*)d_in[15];
    const float* c4_dir = (const float*)d_in[16];
    const float* d4_w  = (const float*)d_in[17];
    const float* cls_w1 = (const float*)d_in[18];
    const float* cls_b1 = (const float*)d_in[19];
    const float* cls_g  = (const float*)d_in[20];
    const float* cls_beta = (const float*)d_in[21];
    const float* cls_w2 = (const float*)d_in[22];
    const float* cls_b2 = (const float*)d_in[23];

    float* ws = (float*)d_ws;
    size_t off = 0;
    auto alloc = [&](size_t n) { float* p = ws + off; off += n; return p; };
    int*   knn1  = (int*)alloc(655360);
    int*   knn2  = (int*)alloc(163840);
    int*   knn3  = (int*)alloc(40960);
    int*   knn4_1 = (int*)alloc(32768);
    int*   knn4_2 = (int*)alloc(8192);
    float* ndir1 = alloc(1966080);
    float* ndir2 = alloc(491520);
    float* ndir3 = alloc(122880);
    float* fm0   = alloc(1048576);
    float* fm1   = alloc(2097152);
    float* fm1p  = alloc(524288);
    float* fm2   = alloc(1048576);
    float* fm3   = alloc(2097152);
    float* fm3p  = alloc(524288);
    float* fout  = alloc(4194304);
    float* convp = alloc(2097152);
    float* gbuf  = alloc(32768);
    float* hbuf  = alloc(8192);
    float* d1t   = alloc(2048);
    float* d2t   = alloc(8192);
    float* d3t   = alloc(32768);
    float* d4t   = alloc(262144);
    float* pz    = alloc(57408);            // BN bins (57344) + barrier cells (64 ints)
    float* p1    = pz;
    float* p2a   = pz + 8192;
    float* p2b   = pz + 24576;
    int*   bar   = (int*)(pz + 57344);
    float* p3    = alloc(65536);

    // ---- prep: knn + transposes + zeroing (1-D grid, no empty blocks) ----
    prep_kernel<<<6085, KNN_TPB, 0, stream>>>(
        vertices, c0_dir, knn1, ndir1, fm0, knn4_1, knn2, ndir2, knn4_2, knn3, ndir3,
        d1_w, d2_w, d3_w, d4_w, d1t, d2t, d3t, d4t, pz);

    NetArgs na;
    na.c1_w = c1_w; na.c1_b = c1_b; na.c1_dir = c1_dir;
    na.c2_w = c2_w; na.c2_b = c2_b; na.c2_dir = c2_dir;
    na.c3_w = c3_w; na.c3_b = c3_b; na.c3_dir = c3_dir;
    na.cls_w1 = cls_w1; na.cls_b1 = cls_b1; na.cls_g = cls_g; na.cls_beta = cls_beta;
    na.cls_w2 = cls_w2; na.cls_b2 = cls_b2;
    na.knn1 = knn1; na.knn2 = knn2; na.knn4_1 = knn4_1; na.knn4_2 = knn4_2;
    na.ndir1 = ndir1; na.ndir2 = ndir2;
    na.fm0 = fm0; na.fm1 = fm1; na.fm1p = fm1p; na.fm2 = fm2; na.fm3 = fm3; na.fm3p = fm3p;
    na.fout = fout; na.convp = convp; na.gbuf = gbuf; na.hbuf = hbuf;
    na.d1t = d1t; na.d2t = d2t; na.d3t = d3t; na.p1 = p1; na.p2a = p2a; na.p2b = p2b;
    na.d4t = d4t; na.p3 = p3;
    na.outp = (float*)d_out;
    na.bar = bar;

    // ---- mega1: stage 1 + stage 2 (960 blocks co-resident; manual grid barriers) ----
    mega1_kernel<<<960, TPB, 0, stream>>>(na);

    // ---- stage 3 fused GEMM+gather (52.7KB LDS, standalone) ----
    s3_fused_kernel<<<dim3(16, 32), TPB, 0, stream>>>(fm3p, c4_w, c4_b, ndir3, knn3, c4_dir, convp, p3);

    // ---- mega2: stage-3 reduction GEMM + classifier ----
    mega2_kernel<<<960, TPB, 0, stream>>>(na);
}

// Round 23
// 319.993 us; speedup vs baseline: 4.5053x; 4.5053x over previous
//
#include <hip/hip_runtime.h>

#define TPB 256
#define KNN_TPB 512
static inline int nblk(long n) { return (int)((n + TPB - 1) / TPB); }

#define FINF 3.402823466e38f

// ---------------- KNN body: radix-select + fused epilogues (K=20 fixed) ----------------
// Unguarded compacted bisection (r16 lesson: wave-uniform guards serialize).
template <int NS, bool WDIR, bool CSURF, int K2>
__device__ __forceinline__ void knn_body(int bx, int b, const float* __restrict__ vin,
                                         int* __restrict__ knn, float* __restrict__ ndir,
                                         int V_out, const float* __restrict__ c0dir,
                                         float* __restrict__ fm0, int V2, int* __restrict__ knn4,
                                         float4* pts, int (*sidx)[20], float (*sdir)[20][3],
                                         unsigned (*cdist)[256], unsigned short (*cidx)[256]) {
    constexpr int K = 20;
    constexpr int VF = NS * 64;
    const float* vb = vin + (size_t)b * 3072; // (3, 1024) layout
    for (int j = threadIdx.x; j < VF; j += blockDim.x) {
        float x = vb[j], y = vb[1024 + j], z = vb[2048 + j];
        pts[j] = make_float4(x, y, z, x * x + y * y + z * z);
    }
    __syncthreads();
    int lane = threadIdx.x & 63;
    int w = threadIdx.x >> 6;
    int i = bx * 8 + w;
    if (i >= V_out) return;
    float4 pi = pts[i];
    unsigned ud[NS];
    unsigned lmin = 0xFFFFFFFFu;
#pragma unroll
    for (int s = 0; s < NS; ++s) {
        int j = s * 64 + lane;
        float4 pj = pts[j];
        float dist = pi.w + pj.w - 2.f * (pi.x * pj.x + pi.y * pj.y + pi.z * pj.z);
        dist = fmaxf(dist, 0.f); // keep bit-monotone
        unsigned v = (j == i) ? 0xFFFFFFFFu : __float_as_uint(dist);
        ud[s] = v;
        lmin = v < lmin ? v : lmin;
    }
    // pair-min upper bound: 32 disjoint lane-pair mins are real candidates => count(<=M) >= 32 >= K
    unsigned pmin = lmin;
    {
        unsigned o = (unsigned)__shfl_xor((int)pmin, 1, 64);
        pmin = o < pmin ? o : pmin;
    }
    unsigned gmin = lmin, M = pmin;
#pragma unroll
    for (int off = 32; off > 1; off >>= 1) {
        unsigned on = (unsigned)__shfl_xor((int)gmin, off, 64);
        gmin = on < gmin ? on : gmin;
        unsigned om = (unsigned)__shfl_xor((int)M, off, 64);
        M = om > M ? om : M;
    }
    {
        unsigned on = (unsigned)__shfl_xor((int)gmin, 1, 64);
        gmin = on < gmin ? on : gmin;
    }
    int* orow = knn + ((size_t)(b * V_out + i)) * K;
    unsigned long long lmask = (1ull << lane) - 1ull;
    bool done = false;
    if constexpr (NS >= 8) {
        int cnt = 0;
#pragma unroll
        for (int s = 0; s < NS; ++s) {
            unsigned long long mm = __ballot(ud[s] <= M);
            if (ud[s] <= M) {
                int p = cnt + __popcll(mm & lmask);
                if (p < 256) { cdist[w][p] = ud[s]; cidx[w][p] = (unsigned short)(s * 64 + lane); }
            }
            cnt += __popcll(mm);
        }
        if (cnt <= 256) {
            unsigned cd[4];
#pragma unroll
            for (int r = 0; r < 4; ++r) {
                int p = lane + r * 64;
                cd[r] = p < cnt ? cdist[w][p] : 0xFFFFFFFFu;
            }
            unsigned lo = gmin, hi = M + 1u;
            while (hi - lo > 1u) {
                unsigned mid = lo + ((hi - lo) >> 1);
                int c = 0;
#pragma unroll
                for (int r = 0; r < 4; ++r)
                    c += __popcll(__ballot(cd[r] < mid));
                if (c >= K) hi = mid; else lo = mid;
            }
            unsigned T = lo;
            int base = 0;
#pragma unroll
            for (int r = 0; r < 4; ++r) {
                unsigned long long mm = __ballot(cd[r] < T);
                if (cd[r] < T) {
                    int p = base + __popcll(mm & lmask);
                    int j = cidx[w][lane + r * 64];
                    sidx[w][p] = j; orow[p] = j;
                }
                base += __popcll(mm);
            }
            int need = K - base, run = 0;
#pragma unroll
            for (int r = 0; r < 4; ++r) {
                unsigned long long mm = __ballot(cd[r] == T);
                int rr = run + __popcll(mm & lmask);
                if (cd[r] == T && rr < need) {
                    int j = cidx[w][lane + r * 64];
                    sidx[w][base + rr] = j; orow[base + rr] = j;
                }
                run += __popcll(mm);
            }
            done = true;
        }
    }
    if (!done) { // full-width (NS<8 or rare overflow)
        unsigned lo = gmin, hi = M + 1u;
        while (hi - lo > 1u) {
            unsigned mid = lo + ((hi - lo) >> 1);
            int cnt = 0;
#pragma unroll
            for (int s = 0; s < NS; ++s)
                cnt += __popcll(__ballot(ud[s] < mid));
            if (cnt >= K) hi = mid; else lo = mid;
        }
        unsigned T = lo;
        int base = 0;
#pragma unroll
        for (int s = 0; s < NS; ++s) {
            unsigned long long m = __ballot(ud[s] < T);
            if (ud[s] < T) {
                int p = base + __popcll(m & lmask);
                sidx[w][p] = s * 64 + lane;
                orow[p] = s * 64 + lane;
            }
            base += __popcll(m);
        }
        int need = K - base, run = 0;
#pragma unroll
        for (int s = 0; s < NS; ++s) {
            unsigned long long m = __ballot(ud[s] == T);
            int r = run + __popcll(m & lmask);
            if (ud[s] == T && r < need) {
                sidx[w][base + r] = s * 64 + lane;
                orow[base + r] = s * 64 + lane;
            }
            run += __popcll(m);
        }
    }
    // --- epilogues (wave-synchronous LDS reads) ---
    if (WDIR) {
        if (lane < K) {
            int j = sidx[w][lane];
            float4 pj = pts[j];
            float dx = pj.x - pi.x, dy = pj.y - pi.y, dz = pj.z - pi.z;
            float inv = 1.f / fmaxf(sqrtf(dx * dx + dy * dy + dz * dz), 1e-12f);
            float* o = ndir + ((size_t)(b * V_out + i) * K + lane) * 3;
            float nx = dx * inv, ny = dy * inv, nz = dz * inv;
            o[0] = nx; o[1] = ny; o[2] = nz;
            if (CSURF) { sdir[w][lane][0] = nx; sdir[w][lane][1] = ny; sdir[w][lane][2] = nz; }
        }
        if (CSURF && lane < 32) {
            int c = lane;
            float d0 = c0dir[c], d1 = c0dir[32 + c], d2 = c0dir[64 + c];
            float inv = 1.f / fmaxf(sqrtf(d0 * d0 + d1 * d1 + d2 * d2), 1e-12f);
            d0 *= inv; d1 *= inv; d2 *= inv;
            float m = 0.f;
            for (int n = 0; n < K; ++n) {
                float th = sdir[w][n][0] * d0 + sdir[w][n][1] * d1 + sdir[w][n][2] * d2;
                m = fmaxf(m, th);
            }
            fm0[(size_t)(b * V_out + i) * 32 + c] = m;
        }
    }
    if (K2 > 0 && i < V2) {
        float dsel = FINF;
        int jsel = 0x7FFFFFFF;
        if (lane < K) {
            jsel = sidx[w][lane];
            float4 pj = pts[jsel];
            dsel = fmaxf(pi.w + pj.w - 2.f * (pi.x * pj.x + pi.y * pj.y + pi.z * pj.z), 0.f);
        }
        int rank = 0;
        for (int m = 0; m < K; ++m) {
            float dm = __shfl(dsel, m, 64);
            int jm = __shfl(jsel, m, 64);
            rank += (dm < dsel || (dm == dsel && jm < jsel)) ? 1 : 0;
        }
        if (lane < K && rank < K2) knn4[((size_t)(b * V2 + i)) * K2 + rank] = jsel;
    }
}

// ---------------- prep: knn stages + weight transposes + BN-bin zeroing, one launch ----------------
__global__ __launch_bounds__(KNN_TPB, 1) void prep_kernel(const float* __restrict__ vin, const float* __restrict__ c0dir,
                                                          int* __restrict__ knn1, float* __restrict__ ndir1,
                                                          float* __restrict__ fm0, int* __restrict__ knn4_1,
                                                          int* __restrict__ knn2, float* __restrict__ ndir2,
                                                          int* __restrict__ knn4_2,
                                                          int* __restrict__ knn3, float* __restrict__ ndir3,
                                                          const float* __restrict__ d1, const float* __restrict__ d2,
                                                          const float* __restrict__ d3, const float* __restrict__ d4,
                                                          float* __restrict__ o1, float* __restrict__ o2,
                                                          float* __restrict__ o3, float* __restrict__ o4,
                                                          float* __restrict__ pz) {
    __shared__ float4 pts[1024];
    __shared__ int sidx[8][20];
    __shared__ float sdir[8][20][3];
    __shared__ unsigned cdist[8][256];
    __shared__ unsigned short cidx[8][256];
    int bx = blockIdx.x, b = blockIdx.y;
    if (bx < 128) {
        knn_body<16, true, true, 4>(bx, b, vin, knn1, ndir1, 1024, c0dir, fm0, 256, knn4_1,
                                    pts, sidx, sdir, cdist, cidx);
        return;
    }
    if (bx < 160) {
        knn_body<4, true, false, 4>(bx - 128, b, vin, knn2, ndir2, 256, nullptr, nullptr, 64, knn4_2,
                                    pts, sidx, sdir, cdist, cidx);
        return;
    }
    if (bx < 168) {
        knn_body<1, true, false, 0>(bx - 160, b, vin, knn3, ndir3, 64, nullptr, nullptr, 0, nullptr,
                                    pts, sidx, sdir, cdist, cidx);
        return;
    }
    if (b != 0) return;
    if (bx < 764) {
        int t = (bx - 168) * KNN_TPB + threadIdx.x;
        if (t < 2048) { int r = t / 32, c = t % 32; o1[c * 64 + r] = d1[t]; return; }
        int t2 = t - 2048;
        if (t2 < 8192) { int r = t2 / 64, c = t2 % 64; o2[c * 128 + r] = d2[t2]; return; }
        int t3 = t2 - 8192;
        if (t3 < 32768) { int r = t3 / 128, c = t3 % 128; o3[c * 256 + r] = d3[t3]; return; }
        int t4 = t3 - 32768;
        if (t4 < 262144) { int r = t4 / 256, c = t4 % 256; o4[c * 1024 + r] = d4[t4]; }
        return;
    }
    int t5 = (bx - 764) * KNN_TPB + threadIdx.x;
    if (t5 < 57344) pz[t5] = 0.f; // stage-1/2 BN bins (p1 + p2a + p2b)
}

// ---------------- LDS-tiled GEMM 64x64, BK=32 ----------------
// MODE 0: out = A@W + bias.  MODE 1: bnrelu(conv) + A@W (BN finalized in-kernel,
// parallel over 256 threads).  MODE 2: MODE 1 + per-batch column-max -> gbuf.
template <int MODE>
__global__ __launch_bounds__(TPB) void gemm64_kernel(const float* __restrict__ A, const float* __restrict__ W,
                                                     const float* __restrict__ bias,
                                                     const float* __restrict__ conv, const float* __restrict__ partial,
                                                     float* __restrict__ out, int M, int N, int K, int nsplit) {
    __shared__ float As[64][36];
    __shared__ float Bs[32][68];
    __shared__ float smean[64], sinv[64];
    int t = threadIdx.x;
    int tx = t & 15, ty = t >> 4;
    int colbase = blockIdx.x * 64, rowbase = blockIdx.y * 64;
    int r0 = ty * 4, c0 = tx * 4;
    if constexpr (MODE >= 1) {
        __shared__ double sred[2][4][64];
        int cc = t & 63, g = t >> 6;
        double s = 0.0, ss = 0.0;
        for (int sp = g; sp < nsplit; sp += 4) {
            s += partial[(size_t)sp * 2 * N + colbase + cc];
            ss += partial[(size_t)sp * 2 * N + N + colbase + cc];
        }
        sred[0][g][cc] = s; sred[1][g][cc] = ss;
        __syncthreads();
        if (t < 64) {
            double S = sred[0][0][t] + sred[0][1][t] + sred[0][2][t] + sred[0][3][t];
            double SS = sred[1][0][t] + sred[1][1][t] + sred[1][2][t] + sred[1][3][t];
            double mean = S / M;
            double var = SS / M - mean * mean;
            if (var < 0) var = 0;
            smean[t] = (float)mean;
            sinv[t] = rsqrtf((float)var + 1e-5f);
        }
        __syncthreads();
    }
    float4 acc0, acc1, acc2, acc3;
    if (MODE == 0) {
        float4 bv = *(const float4*)(bias + colbase + c0);
        acc0 = bv; acc1 = bv; acc2 = bv; acc3 = bv;
    } else {
        acc0 = make_float4(0.f, 0.f, 0.f, 0.f); acc1 = acc0; acc2 = acc0; acc3 = acc0;
    }
    for (int kt = 0; kt < K; kt += 32) {
#pragma unroll
        for (int l = 0; l < 2; ++l) {
            int lin = t + l * 256;
            int ar = lin >> 3, ak = (lin & 7) << 2;
            *(float4*)&As[ar][ak] = *(const float4*)(A + (size_t)(rowbase + ar) * K + kt + ak);
            int br = lin >> 4, bn = (lin & 15) << 2;
            *(float4*)&Bs[br][bn] = *(const float4*)(W + (size_t)(kt + br) * N + colbase + bn);
        }
        __syncthreads();
#pragma unroll 4
        for (int k = 0; k < 32; ++k) {
            float4 bv = *(const float4*)&Bs[k][c0];
            float a0 = As[r0][k], a1 = As[r0 + 1][k], a2 = As[r0 + 2][k], a3 = As[r0 + 3][k];
            acc0.x += a0 * bv.x; acc0.y += a0 * bv.y; acc0.z += a0 * bv.z; acc0.w += a0 * bv.w;
            acc1.x += a1 * bv.x; acc1.y += a1 * bv.y; acc1.z += a1 * bv.z; acc1.w += a1 * bv.w;
            acc2.x += a2 * bv.x; acc2.y += a2 * bv.y; acc2.z += a2 * bv.z; acc2.w += a2 * bv.w;
            acc3.x += a3 * bv.x; acc3.y += a3 * bv.y; acc3.z += a3 * bv.z; acc3.w += a3 * bv.w;
        }
        __syncthreads();
    }
    float4 accs[4] = {acc0, acc1, acc2, acc3};
    if constexpr (MODE >= 1) {
        float4 mean = *(const float4*)&smean[c0];
        float4 inv = *(const float4*)&sinv[c0];
#pragma unroll
        for (int rr = 0; rr < 4; ++rr) {
            float4 cv = *(const float4*)(conv + (size_t)(rowbase + r0 + rr) * N + colbase + c0);
            accs[rr].x += fmaxf((cv.x - mean.x) * inv.x, 0.f);
            accs[rr].y += fmaxf((cv.y - mean.y) * inv.y, 0.f);
            accs[rr].z += fmaxf((cv.z - mean.z) * inv.z, 0.f);
            accs[rr].w += fmaxf((cv.w - mean.w) * inv.w, 0.f);
        }
    }
    if constexpr (MODE == 2) {
        __shared__ float redmax[16][68];
        float4 tm;
        tm.x = fmaxf(fmaxf(accs[0].x, accs[1].x), fmaxf(accs[2].x, accs[3].x));
        tm.y = fmaxf(fmaxf(accs[0].y, accs[1].y), fmaxf(accs[2].y, accs[3].y));
        tm.z = fmaxf(fmaxf(accs[0].z, accs[1].z), fmaxf(accs[2].z, accs[3].z));
        tm.w = fmaxf(fmaxf(accs[0].w, accs[1].w), fmaxf(accs[2].w, accs[3].w));
        *(float4*)&redmax[ty][c0] = tm;
        __syncthreads();
        if (t < 64) {
            float m = redmax[0][t];
#pragma unroll
            for (int g = 1; g < 16; ++g) m = fmaxf(m, redmax[g][t]);
            out[(size_t)blockIdx.y * N + colbase + t] = m;
        }
    } else {
#pragma unroll
        for (int rr = 0; rr < 4; ++rr)
            *(float4*)(out + (size_t)(rowbase + r0 + rr) * N + colbase + c0) = accs[rr];
    }
}

// ---------------- conv_layer: center + max_n(theta * support), 4 ch/thread ----------------
// FUSE: accumulate BN (sum, sumsq) per channel via LDS reduce + 64-bin global
// atomics (Cout <= 256, exact grids only).
template <bool FUSE>
__global__ __launch_bounds__(TPB) void conv_act_kernel(const float* __restrict__ ndir, const int* __restrict__ knn,
                                const float* __restrict__ fout, const float* __restrict__ dir,
                                float* __restrict__ out, int B, int Vst, int K, int Cout,
                                float* __restrict__ bnpart) {
    __shared__ float sAcc[2][256];
    int t = blockIdx.x * blockDim.x + threadIdx.x;
    int nc4 = Cout >> 2;
    bool active = t < B * Vst * nc4;
    float4 o = make_float4(0.f, 0.f, 0.f, 0.f);
    int c4 = 0;
    if (active) {
        int row = t / nc4; c4 = (t % nc4) * 4;
        int b = row / Vst;
        float4 D0 = *(const float4*)(dir + c4);
        float4 D1 = *(const float4*)(dir + Cout + c4);
        float4 D2 = *(const float4*)(dir + 2 * Cout + c4);
        float4 e0, e1, e2;
        {
            float i0 = 1.f / fmaxf(sqrtf(D0.x * D0.x + D1.x * D1.x + D2.x * D2.x), 1e-12f);
            float i1 = 1.f / fmaxf(sqrtf(D0.y * D0.y + D1.y * D1.y + D2.y * D2.y), 1e-12f);
            float i2 = 1.f / fmaxf(sqrtf(D0.z * D0.z + D1.z * D1.z + D2.z * D2.z), 1e-12f);
            float i3 = 1.f / fmaxf(sqrtf(D0.w * D0.w + D1.w * D1.w + D2.w * D2.w), 1e-12f);
            e0 = make_float4(D0.x * i0, D0.y * i1, D0.z * i2, D0.w * i3);
            e1 = make_float4(D1.x * i0, D1.y * i1, D1.z * i2, D1.w * i3);
            e2 = make_float4(D2.x * i0, D2.y * i1, D2.z * i2, D2.w * i3);
        }
        int Cw = 2 * Cout;
        float4 m = make_float4(-FINF, -FINF, -FINF, -FINF);
        const float* nd = ndir + (size_t)row * K * 3;
        const int* kr = knn + (size_t)row * K;
        for (int n = 0; n < K; ++n) {
            int j = kr[n];
            float n0 = nd[n * 3], n1 = nd[n * 3 + 1], n2 = nd[n * 3 + 2];
            float4 s = *(const float4*)(fout + ((size_t)(b * Vst + j)) * Cw + Cout + c4);
            float t0 = fmaxf(n0 * e0.x + n1 * e1.x + n2 * e2.x, 0.f);
            float t1 = fmaxf(n0 * e0.y + n1 * e1.y + n2 * e2.y, 0.f);
            float t2 = fmaxf(n0 * e0.z + n1 * e1.z + n2 * e2.z, 0.f);
            float t3 = fmaxf(n0 * e0.w + n1 * e1.w + n2 * e2.w, 0.f);
            m.x = fmaxf(m.x, t0 * s.x);
            m.y = fmaxf(m.y, t1 * s.y);
            m.z = fmaxf(m.z, t2 * s.z);
            m.w = fmaxf(m.w, t3 * s.w);
        }
        float4 ctr = *(const float4*)(fout + (size_t)row * Cw + c4);
        o = make_float4(ctr.x + m.x, ctr.y + m.y, ctr.z + m.z, ctr.w + m.w);
        *(float4*)(out + (size_t)row * Cout + c4) = o;
    }
    if constexpr (FUSE) {
        for (int i = threadIdx.x; i < 2 * Cout; i += TPB) ((float*)sAcc)[i < Cout ? i : 256 + (i - Cout)] = 0.f;
        __syncthreads();
        if (active) {
            atomicAdd(&sAcc[0][c4 + 0], o.x); atomicAdd(&sAcc[1][c4 + 0], o.x * o.x);
            atomicAdd(&sAcc[0][c4 + 1], o.y); atomicAdd(&sAcc[1][c4 + 1], o.y * o.y);
            atomicAdd(&sAcc[0][c4 + 2], o.z); atomicAdd(&sAcc[1][c4 + 2], o.z * o.z);
            atomicAdd(&sAcc[0][c4 + 3], o.w); atomicAdd(&sAcc[1][c4 + 3], o.w * o.w);
        }
        __syncthreads();
        int bin = blockIdx.x & 63;
        for (int i = threadIdx.x; i < Cout; i += TPB) {
            atomicAdd(&bnpart[(size_t)bin * 2 * Cout + i], sAcc[0][i]);
            atomicAdd(&bnpart[(size_t)bin * 2 * Cout + Cout + i], sAcc[1][i]);
        }
    }
}

// ---------------- stage-3 FUSED: c4 GEMM (center+support) + conv_act + BN partials ----------------
// grid (16, 32): block = one batch (64 rows) x 64-channel slice. Both 64x64 tiles
// computed with shared A-staging; support tile parked in LDS; 20-NN gather is
// LDS-local (neighbors batch-local); BN partials plain-stored, bin = batch.
__global__ __launch_bounds__(TPB) void s3_fused_kernel(const float* __restrict__ A, const float* __restrict__ W,
                                                       const float* __restrict__ bias,
                                                       const float* __restrict__ ndir, const int* __restrict__ knn,
                                                       const float* __restrict__ dir,
                                                       float* __restrict__ convp, float* __restrict__ bnpart) {
    constexpr int K = 256, N = 2048, Cout = 1024, KN = 20;
    __shared__ float As[64][36];
    __shared__ float Bc[32][68];
    __shared__ float Bsup[32][68];
    __shared__ float S[64][68];
    __shared__ float red[2][16][68];
    int t = threadIdx.x;
    int tx = t & 15, ty = t >> 4;
    int r0 = ty * 4, c0 = tx * 4;
    int batch = blockIdx.y;
    int colbase = blockIdx.x * 64;
    int rowbase = batch * 64;
    float4 accC[4], accS[4];
    {
        float4 bc = *(const float4*)(bias + colbase + c0);
        float4 bs = *(const float4*)(bias + Cout + colbase + c0);
#pragma unroll
        for (int rr = 0; rr < 4; ++rr) { accC[rr] = bc; accS[rr] = bs; }
    }
    for (int kt = 0; kt < K; kt += 32) {
#pragma unroll
        for (int l = 0; l < 2; ++l) {
            int lin = t + l * 256;
            int ar = lin >> 3, ak = (lin & 7) << 2;
            *(float4*)&As[ar][ak] = *(const float4*)(A + (size_t)(rowbase + ar) * K + kt + ak);
            int br = lin >> 4, bn = (lin & 15) << 2;
            *(float4*)&Bc[br][bn] = *(const float4*)(W + (size_t)(kt + br) * N + colbase + bn);
            *(float4*)&Bsup[br][bn] = *(const float4*)(W + (size_t)(kt + br) * N + Cout + colbase + bn);
        }
        __syncthreads();
#pragma unroll 4
        for (int k = 0; k < 32; ++k) {
            float4 bc = *(const float4*)&Bc[k][c0];
            float4 bs = *(const float4*)&Bsup[k][c0];
            float a0 = As[r0][k], a1 = As[r0 + 1][k], a2 = As[r0 + 2][k], a3 = As[r0 + 3][k];
            accC[0].x += a0 * bc.x; accC[0].y += a0 * bc.y; accC[0].z += a0 * bc.z; accC[0].w += a0 * bc.w;
            accC[1].x += a1 * bc.x; accC[1].y += a1 * bc.y; accC[1].z += a1 * bc.z; accC[1].w += a1 * bc.w;
            accC[2].x += a2 * bc.x; accC[2].y += a2 * bc.y; accC[2].z += a2 * bc.z; accC[2].w += a2 * bc.w;
            accC[3].x += a3 * bc.x; accC[3].y += a3 * bc.y; accC[3].z += a3 * bc.z; accC[3].w += a3 * bc.w;
            accS[0].x += a0 * bs.x; accS[0].y += a0 * bs.y; accS[0].z += a0 * bs.z; accS[0].w += a0 * bs.w;
            accS[1].x += a1 * bs.x; accS[1].y += a1 * bs.y; accS[1].z += a1 * bs.z; accS[1].w += a1 * bs.w;
            accS[2].x += a2 * bs.x; accS[2].y += a2 * bs.y; accS[2].z += a2 * bs.z; accS[2].w += a2 * bs.w;
            accS[3].x += a3 * bs.x; accS[3].y += a3 * bs.y; accS[3].z += a3 * bs.z; accS[3].w += a3 * bs.w;
        }
        __syncthreads();
    }
#pragma unroll
    for (int rr = 0; rr < 4; ++rr)
        *(float4*)&S[r0 + rr][c0] = accS[rr];
    __syncthreads();
    int c = colbase + c0;
    float4 D0 = *(const float4*)(dir + c);
    float4 D1 = *(const float4*)(dir + Cout + c);
    float4 D2 = *(const float4*)(dir + 2 * Cout + c);
    float4 e0, e1, e2;
    {
        float i0 = 1.f / fmaxf(sqrtf(D0.x * D0.x + D1.x * D1.x + D2.x * D2.x), 1e-12f);
        float i1 = 1.f / fmaxf(sqrtf(D0.y * D0.y + D1.y * D1.y + D2.y * D2.y), 1e-12f);
        float i2 = 1.f / fmaxf(sqrtf(D0.z * D0.z + D1.z * D1.z + D2.z * D2.z), 1e-12f);
        float i3 = 1.f / fmaxf(sqrtf(D0.w * D0.w + D1.w * D1.w + D2.w * D2.w), 1e-12f);
        e0 = make_float4(D0.x * i0, D0.y * i1, D0.z * i2, D0.w * i3);
        e1 = make_float4(D1.x * i0, D1.y * i1, D1.z * i2, D1.w * i3);
        e2 = make_float4(D2.x * i0, D2.y * i1, D2.z * i2, D2.w * i3);
    }
    float4 sum = make_float4(0.f, 0.f, 0.f, 0.f);
    float4 ssum = make_float4(0.f, 0.f, 0.f, 0.f);
#pragma unroll
    for (int rr = 0; rr < 4; ++rr) {
        int row = rowbase + r0 + rr;
        float4 m = make_float4(-FINF, -FINF, -FINF, -FINF);
        const float* nd = ndir + (size_t)row * KN * 3;
        const int* kr = knn + (size_t)row * KN;
        for (int n = 0; n < KN; ++n) {
            int j = kr[n];
            float n0 = nd[n * 3], n1 = nd[n * 3 + 1], n2 = nd[n * 3 + 2];
            float4 s = *(const float4*)&S[j][c0];
            float t0 = fmaxf(n0 * e0.x + n1 * e1.x + n2 * e2.x, 0.f);
            float t1 = fmaxf(n0 * e0.y + n1 * e1.y + n2 * e2.y, 0.f);
            float t2 = fmaxf(n0 * e0.z + n1 * e1.z + n2 * e2.z, 0.f);
            float t3 = fmaxf(n0 * e0.w + n1 * e1.w + n2 * e2.w, 0.f);
            m.x = fmaxf(m.x, t0 * s.x);
            m.y = fmaxf(m.y, t1 * s.y);
            m.z = fmaxf(m.z, t2 * s.z);
            m.w = fmaxf(m.w, t3 * s.w);
        }
        float4 o = make_float4(accC[rr].x + m.x, accC[rr].y + m.y, accC[rr].z + m.z, accC[rr].w + m.w);
        *(float4*)(convp + (size_t)row * Cout + colbase + c0) = o;
        sum.x += o.x; sum.y += o.y; sum.z += o.z; sum.w += o.w;
        ssum.x += o.x * o.x; ssum.y += o.y * o.y; ssum.z += o.z * o.z; ssum.w += o.w * o.w;
    }
    *(float4*)&red[0][ty][c0] = sum;
    *(float4*)&red[1][ty][c0] = ssum;
    __syncthreads();
    if (t < 64) {
        float Ssum = 0.f, SSsum = 0.f;
#pragma unroll
        for (int g = 0; g < 16; ++g) { Ssum += red[0][g][t]; SSsum += red[1][g][t]; }
        bnpart[(size_t)batch * 2048 + colbase + t] = Ssum;
        bnpart[(size_t)batch * 2048 + 1024 + colbase + t] = SSsum;
    }
}

// ---------------- pool: max over 4 NN features ----------------
__global__ __launch_bounds__(TPB) void pool_max_kernel(const float* __restrict__ fm, const int* __restrict__ knn4,
                                float* __restrict__ out, int B, int Vin, int pn, int C) {
    int t = blockIdx.x * blockDim.x + threadIdx.x;
    if (t >= B * pn * C) return;
    int row = t / C, c = t % C;
    int b = row / pn;
    const int* kr = knn4 + (size_t)row * 4;
    float m = fmaxf(fmaxf(fm[((size_t)(b * Vin + kr[0])) * C + c], fm[((size_t)(b * Vin + kr[1])) * C + c]),
                    fmaxf(fm[((size_t)(b * Vin + kr[2])) * C + c], fm[((size_t)(b * Vin + kr[3])) * C + c]));
    out[t] = m;
}

// ---------------- wave-per-output: out[r,c] = in[r,:]@w[c,:] + bias[c] ----------------
__global__ __launch_bounds__(TPB, 1) void gemm_t_wave_kernel(const float* __restrict__ in, const float* __restrict__ w,
                                   const float* __restrict__ bias, float* __restrict__ out,
                                   int rows, int Cin, int Cout) {
    int wid = (blockIdx.x * blockDim.x + threadIdx.x) >> 6;
    int lane = threadIdx.x & 63;
    if (wid >= rows * Cout) return;
    int r = wid / Cout, c = wid % Cout;
    const float4* a = (const float4*)(in + (size_t)r * Cin);
    const float4* wr = (const float4*)(w + (size_t)c * Cin);
    int n4 = Cin >> 2;
    float acc = 0.f;
    for (int k = lane; k < n4; k += 64) {
        float4 av = a[k], wv = wr[k];
        acc += av.x * wv.x + av.y * wv.y + av.z * wv.z + av.w * wv.w;
    }
#pragma unroll
    for (int off = 32; off > 0; off >>= 1) acc += __shfl_xor(acc, off, 64);
    if (lane == 0) out[wid] = acc + bias[c];
}

// ---------------- fused classifier tail ----------------
__global__ __launch_bounds__(TPB, 1) void cls_fused_kernel(const float* __restrict__ h,
                                 const float* __restrict__ gam, const float* __restrict__ beta,
                                 const float* __restrict__ w2, const float* __restrict__ b2,
                                 float* __restrict__ out) {
    __shared__ float smean[256], sa[256];
    int t = threadIdx.x;
    {
        float s = 0.f, ss = 0.f;
        for (int b = 0; b < 32; ++b) {
            float v = h[(size_t)b * 256 + t];
            s += v; ss += v * v;
        }
        float mn = s / 32.f;
        float var = ss / 32.f - mn * mn;
        if (var < 0.f) var = 0.f;
        smean[t] = mn;
        sa[t] = rsqrtf(var + 1e-5f) * gam[t];
    }
    __syncthreads();
    int wid = blockIdx.x * 4 + (t >> 6);
    int lane = t & 63;
    if (wid >= 32 * 40) return;
    int b = wid / 40, o = wid % 40;
    float acc = 0.f;
#pragma unroll
    for (int kk = 0; kk < 4; ++kk) {
        int c = lane + kk * 64;
        float v = fmaxf((h[b * 256 + c] - smean[c]) * sa[c] + beta[c], 0.f);
        acc += v * w2[o * 256 + c];
    }
#pragma unroll
    for (int off = 32; off > 0; off >>= 1) acc += __shfl_xor(acc, off, 64);
    if (lane == 0) out[wid] = acc + b2[o];
}

extern "C" void kernel_launch(void* const* d_in, const int* in_sizes, int n_in,
                              void* d_out, int out_size, void* d_ws, size_t ws_size,
                              hipStream_t stream) {
    const float* vertices = (const float*)d_in[0];
    const float* c0_dir = (const float*)d_in[1];
    const float* c1_w  = (const float*)d_in[2];
    const float* c1_b  = (const float*)d_in[3];
    const float* c1_dir = (const float*)d_in[4];
    const float* d1_w  = (const float*)d_in[5];
    const float* c2_w  = (const float*)d_in[6];
    const float* c2_b  = (const float*)d_in[7];
    const float* c2_dir = (const float*)d_in[8];
    const float* d2_w  = (const float*)d_in[9];
    const float* c3_w  = (const float*)d_in[10];
    const float* c3_b  = (const float*)d_in[11];
    const float* c3_dir = (const float*)d_in[12];
    const float* d3_w  = (const float*)d_in[13];
    const float* c4_w  = (const float*)d_in[14];
    const float* c4_b  = (const float*)d_in[15];
    const float* c4_dir = (const float*)d_in[16];
    const float* d4_w  = (const float*)d_in[17];
    const float* cls_w1 = (const float*)d_in[18];
    const float* cls_b1 = (const float*)d_in[19];
    const float* cls_g  = (const float*)d_in[20];
    const float* cls_beta = (const float*)d_in[21];
    const float* cls_w2 = (const float*)d_in[22];
    const float* cls_b2 = (const float*)d_in[23];

    const int B = 32;
    float* ws = (float*)d_ws;
    size_t off = 0;
    auto alloc = [&](size_t n) { float* p = ws + off; off += n; return p; };
    int*   knn1  = (int*)alloc(655360);     // B*1024*20
    int*   knn2  = (int*)alloc(163840);     // B*256*20
    int*   knn3  = (int*)alloc(40960);      // B*64*20
    int*   knn4_1 = (int*)alloc(32768);     // B*256*4
    int*   knn4_2 = (int*)alloc(8192);      // B*64*4
    float* ndir1 = alloc(1966080);          // B*1024*20*3
    float* ndir2 = alloc(491520);           // B*256*20*3
    float* ndir3 = alloc(122880);           // B*64*20*3
    float* fm0   = alloc(1048576);          // B*1024*32
    float* fm1   = alloc(2097152);          // B*1024*64
    float* fm1p  = alloc(524288);           // B*256*64
    float* fm2   = alloc(1048576);          // B*256*128
    float* fm3   = alloc(2097152);          // B*256*256
    float* fm3p  = alloc(524288);           // B*64*256
    float* fout  = alloc(4194304);          // stage-1/2 fout
    float* convp = alloc(2097152);          // pre-BN conv out
    float* gbuf  = alloc(32768);            // B*1024
    float* hbuf  = alloc(8192);             // B*256
    float* d1t   = alloc(2048);             // 32 x 64
    float* d2t   = alloc(8192);             // 64 x 128
    float* d3t   = alloc(32768);            // 128 x 256
    float* d4t   = alloc(262144);           // 256 x 1024
    float* pz    = alloc(57344);            // zeroed BN bins: p1(8K) + p2a(16K) + p2b(32K)
    float* p1    = pz;                      // 64 bins x 2 x 64
    float* p2a   = pz + 8192;               // 64 bins x 2 x 128
    float* p2b   = pz + 24576;              // 64 bins x 2 x 256
    float* p3    = alloc(65536);            // stage-3 partials: 32 bins x 2 x 1024 (plain stores)

    // ---- prep: all knn stages + transposes + BN-bin zeroing, one launch ----
    prep_kernel<<<dim3(876, B), KNN_TPB, 0, stream>>>(
        vertices, c0_dir, knn1, ndir1, fm0, knn4_1, knn2, ndir2, knn4_2, knn3, ndir3,
        d1_w, d2_w, d3_w, d4_w, d1t, d2t, d3t, d4t, pz);

    // ---- stage 1 (V=1024) ----
    gemm64_kernel<0><<<dim3(2, 512), TPB, 0, stream>>>(fm0, c1_w, c1_b, nullptr, nullptr, fout, B * 1024, 128, 32, 0);
    conv_act_kernel<true><<<nblk((long)B * 1024 * 16), TPB, 0, stream>>>(ndir1, knn1, fout, c1_dir, convp, B, 1024, 20, 64, p1);
    gemm64_kernel<1><<<dim3(1, 512), TPB, 0, stream>>>(fm0, d1t, nullptr, convp, p1, fm1, B * 1024, 64, 32, 64);
    pool_max_kernel<<<nblk((long)B * 256 * 64), TPB, 0, stream>>>(fm1, knn4_1, fm1p, B, 1024, 256, 64);

    // ---- stage 2 (V=256) ----
    gemm64_kernel<0><<<dim3(4, 128), TPB, 0, stream>>>(fm1p, c2_w, c2_b, nullptr, nullptr, fout, B * 256, 256, 64, 0);
    conv_act_kernel<true><<<nblk((long)B * 256 * 32), TPB, 0, stream>>>(ndir2, knn2, fout, c2_dir, convp, B, 256, 20, 128, p2a);
    gemm64_kernel<1><<<dim3(2, 128), TPB, 0, stream>>>(fm1p, d2t, nullptr, convp, p2a, fm2, B * 256, 128, 64, 64);
    gemm64_kernel<0><<<dim3(8, 128), TPB, 0, stream>>>(fm2, c3_w, c3_b, nullptr, nullptr, fout, B * 256, 512, 128, 0);
    conv_act_kernel<true><<<nblk((long)B * 256 * 64), TPB, 0, stream>>>(ndir2, knn2, fout, c3_dir, convp, B, 256, 20, 256, p2b);
    gemm64_kernel<1><<<dim3(4, 128), TPB, 0, stream>>>(fm2, d3t, nullptr, convp, p2b, fm3, B * 256, 256, 128, 64);
    pool_max_kernel<<<nblk((long)B * 64 * 256), TPB, 0, stream>>>(fm3, knn4_2, fm3p, B, 256, 64, 256);

    // ---- stage 3 (V=64): fused c4 GEMM + conv_act + BN partials ----
    s3_fused_kernel<<<dim3(16, 32), TPB, 0, stream>>>(fm3p, c4_w, c4_b, ndir3, knn3, c4_dir, convp, p3);
    gemm64_kernel<2><<<dim3(16, 32), TPB, 0, stream>>>(fm3p, d4t, nullptr, convp, p3, gbuf, B * 64, 1024, 256, 32);

    // ---- classifier ----
    gemm_t_wave_kernel<<<nblk((long)32 * 256 * 64), TPB, 0, stream>>>(gbuf, cls_w1, cls_b1, hbuf, 32, 1024, 256);
    cls_fused_kernel<<<320, TPB, 0, stream>>>(hbuf, cls_g, cls_beta, cls_w2, cls_b2, (float*)d_out);
}

// Round 24
// 312.429 us; speedup vs baseline: 4.6144x; 1.0242x over previous
//
#include <hip/hip_runtime.h>

#define TPB 256
#define KNN_TPB 512
static inline int nblk(long n) { return (int)((n + TPB - 1) / TPB); }

#define FINF 3.402823466e38f

// ---------------- KNN body: radix-select + fused epilogues (K=20 fixed) ----------------
// Unguarded compacted bisection (r16 lesson: wave-uniform guards serialize).
template <int NS, bool WDIR, bool CSURF, int K2>
__device__ __forceinline__ void knn_body(int bx, int b, const float* __restrict__ vin,
                                         int* __restrict__ knn, float* __restrict__ ndir,
                                         int V_out, const float* __restrict__ c0dir,
                                         float* __restrict__ fm0, int V2, int* __restrict__ knn4,
                                         float4* pts, int (*sidx)[20], float (*sdir)[20][3],
                                         unsigned (*cdist)[256], unsigned short (*cidx)[256]) {
    constexpr int K = 20;
    constexpr int VF = NS * 64;
    const float* vb = vin + (size_t)b * 3072; // (3, 1024) layout
    for (int j = threadIdx.x; j < VF; j += blockDim.x) {
        float x = vb[j], y = vb[1024 + j], z = vb[2048 + j];
        pts[j] = make_float4(x, y, z, x * x + y * y + z * z);
    }
    __syncthreads();
    int lane = threadIdx.x & 63;
    int w = threadIdx.x >> 6;
    int i = bx * 8 + w;
    if (i >= V_out) return;
    float4 pi = pts[i];
    unsigned ud[NS];
    unsigned lmin = 0xFFFFFFFFu;
#pragma unroll
    for (int s = 0; s < NS; ++s) {
        int j = s * 64 + lane;
        float4 pj = pts[j];
        float dist = pi.w + pj.w - 2.f * (pi.x * pj.x + pi.y * pj.y + pi.z * pj.z);
        dist = fmaxf(dist, 0.f); // keep bit-monotone
        unsigned v = (j == i) ? 0xFFFFFFFFu : __float_as_uint(dist);
        ud[s] = v;
        lmin = v < lmin ? v : lmin;
    }
    // pair-min upper bound: 32 disjoint lane-pair mins are real candidates => count(<=M) >= 32 >= K
    unsigned pmin = lmin;
    {
        unsigned o = (unsigned)__shfl_xor((int)pmin, 1, 64);
        pmin = o < pmin ? o : pmin;
    }
    unsigned gmin = lmin, M = pmin;
#pragma unroll
    for (int off = 32; off > 1; off >>= 1) {
        unsigned on = (unsigned)__shfl_xor((int)gmin, off, 64);
        gmin = on < gmin ? on : gmin;
        unsigned om = (unsigned)__shfl_xor((int)M, off, 64);
        M = om > M ? om : M;
    }
    {
        unsigned on = (unsigned)__shfl_xor((int)gmin, 1, 64);
        gmin = on < gmin ? on : gmin;
    }
    int* orow = knn + ((size_t)(b * V_out + i)) * K;
    unsigned long long lmask = (1ull << lane) - 1ull;
    bool done = false;
    if constexpr (NS >= 8) {
        int cnt = 0;
#pragma unroll
        for (int s = 0; s < NS; ++s) {
            unsigned long long mm = __ballot(ud[s] <= M);
            if (ud[s] <= M) {
                int p = cnt + __popcll(mm & lmask);
                if (p < 256) { cdist[w][p] = ud[s]; cidx[w][p] = (unsigned short)(s * 64 + lane); }
            }
            cnt += __popcll(mm);
        }
        if (cnt <= 256) {
            unsigned cd[4];
#pragma unroll
            for (int r = 0; r < 4; ++r) {
                int p = lane + r * 64;
                cd[r] = p < cnt ? cdist[w][p] : 0xFFFFFFFFu;
            }
            unsigned lo = gmin, hi = M + 1u;
            while (hi - lo > 1u) {
                unsigned mid = lo + ((hi - lo) >> 1);
                int c = 0;
#pragma unroll
                for (int r = 0; r < 4; ++r)
                    c += __popcll(__ballot(cd[r] < mid));
                if (c >= K) hi = mid; else lo = mid;
            }
            unsigned T = lo;
            int base = 0;
#pragma unroll
            for (int r = 0; r < 4; ++r) {
                unsigned long long mm = __ballot(cd[r] < T);
                if (cd[r] < T) {
                    int p = base + __popcll(mm & lmask);
                    int j = cidx[w][lane + r * 64];
                    sidx[w][p] = j; orow[p] = j;
                }
                base += __popcll(mm);
            }
            int need = K - base, run = 0;
#pragma unroll
            for (int r = 0; r < 4; ++r) {
                unsigned long long mm = __ballot(cd[r] == T);
                int rr = run + __popcll(mm & lmask);
                if (cd[r] == T && rr < need) {
                    int j = cidx[w][lane + r * 64];
                    sidx[w][base + rr] = j; orow[base + rr] = j;
                }
                run += __popcll(mm);
            }
            done = true;
        }
    }
    if (!done) { // full-width (NS<8 or rare overflow)
        unsigned lo = gmin, hi = M + 1u;
        while (hi - lo > 1u) {
            unsigned mid = lo + ((hi - lo) >> 1);
            int cnt = 0;
#pragma unroll
            for (int s = 0; s < NS; ++s)
                cnt += __popcll(__ballot(ud[s] < mid));
            if (cnt >= K) hi = mid; else lo = mid;
        }
        unsigned T = lo;
        int base = 0;
#pragma unroll
        for (int s = 0; s < NS; ++s) {
            unsigned long long m = __ballot(ud[s] < T);
            if (ud[s] < T) {
                int p = base + __popcll(m & lmask);
                sidx[w][p] = s * 64 + lane;
                orow[p] = s * 64 + lane;
            }
            base += __popcll(m);
        }
        int need = K - base, run = 0;
#pragma unroll
        for (int s = 0; s < NS; ++s) {
            unsigned long long m = __ballot(ud[s] == T);
            int r = run + __popcll(m & lmask);
            if (ud[s] == T && r < need) {
                sidx[w][base + r] = s * 64 + lane;
                orow[base + r] = s * 64 + lane;
            }
            run += __popcll(m);
        }
    }
    // --- epilogues (wave-synchronous LDS reads) ---
    if (WDIR) {
        if (lane < K) {
            int j = sidx[w][lane];
            float4 pj = pts[j];
            float dx = pj.x - pi.x, dy = pj.y - pi.y, dz = pj.z - pi.z;
            float inv = 1.f / fmaxf(sqrtf(dx * dx + dy * dy + dz * dz), 1e-12f);
            float* o = ndir + ((size_t)(b * V_out + i) * K + lane) * 3;
            float nx = dx * inv, ny = dy * inv, nz = dz * inv;
            o[0] = nx; o[1] = ny; o[2] = nz;
            if (CSURF) { sdir[w][lane][0] = nx; sdir[w][lane][1] = ny; sdir[w][lane][2] = nz; }
        }
        if (CSURF && lane < 32) {
            int c = lane;
            float d0 = c0dir[c], d1 = c0dir[32 + c], d2 = c0dir[64 + c];
            float inv = 1.f / fmaxf(sqrtf(d0 * d0 + d1 * d1 + d2 * d2), 1e-12f);
            d0 *= inv; d1 *= inv; d2 *= inv;
            float m = 0.f;
            for (int n = 0; n < K; ++n) {
                float th = sdir[w][n][0] * d0 + sdir[w][n][1] * d1 + sdir[w][n][2] * d2;
                m = fmaxf(m, th);
            }
            fm0[(size_t)(b * V_out + i) * 32 + c] = m;
        }
    }
    if (K2 > 0 && i < V2) {
        float dsel = FINF;
        int jsel = 0x7FFFFFFF;
        if (lane < K) {
            jsel = sidx[w][lane];
            float4 pj = pts[jsel];
            dsel = fmaxf(pi.w + pj.w - 2.f * (pi.x * pj.x + pi.y * pj.y + pi.z * pj.z), 0.f);
        }
        int rank = 0;
        for (int m = 0; m < K; ++m) {
            float dm = __shfl(dsel, m, 64);
            int jm = __shfl(jsel, m, 64);
            rank += (dm < dsel || (dm == dsel && jm < jsel)) ? 1 : 0;
        }
        if (lane < K && rank < K2) knn4[((size_t)(b * V2 + i)) * K2 + rank] = jsel;
    }
}

// ---------------- prep (1-D grid, no empty blocks): knn stages + transposes + BN-bin zeroing ----------------
// bx < 5376: knn work (b = bx/168, r = bx%168: r<128 knn1, r<160 knn2, else knn3).
// bx >= 5376: linear chain of transposes (305152 threads) then zeroing (57344).
__global__ __launch_bounds__(KNN_TPB, 1) void prep_kernel(const float* __restrict__ vin, const float* __restrict__ c0dir,
                                                          int* __restrict__ knn1, float* __restrict__ ndir1,
                                                          float* __restrict__ fm0, int* __restrict__ knn4_1,
                                                          int* __restrict__ knn2, float* __restrict__ ndir2,
                                                          int* __restrict__ knn4_2,
                                                          int* __restrict__ knn3, float* __restrict__ ndir3,
                                                          const float* __restrict__ d1, const float* __restrict__ d2,
                                                          const float* __restrict__ d3, const float* __restrict__ d4,
                                                          float* __restrict__ o1, float* __restrict__ o2,
                                                          float* __restrict__ o3, float* __restrict__ o4,
                                                          float* __restrict__ pz) {
    __shared__ float4 pts[1024];
    __shared__ int sidx[8][20];
    __shared__ float sdir[8][20][3];
    __shared__ unsigned cdist[8][256];
    __shared__ unsigned short cidx[8][256];
    int bx = blockIdx.x;
    if (bx < 5376) {
        int b = bx / 168;
        int r = bx - b * 168;
        if (r < 128) {
            knn_body<16, true, true, 4>(r, b, vin, knn1, ndir1, 1024, c0dir, fm0, 256, knn4_1,
                                        pts, sidx, sdir, cdist, cidx);
        } else if (r < 160) {
            knn_body<4, true, false, 4>(r - 128, b, vin, knn2, ndir2, 256, nullptr, nullptr, 64, knn4_2,
                                        pts, sidx, sdir, cdist, cidx);
        } else {
            knn_body<1, true, false, 0>(r - 160, b, vin, knn3, ndir3, 64, nullptr, nullptr, 0, nullptr,
                                        pts, sidx, sdir, cdist, cidx);
        }
        return;
    }
    int t = (bx - 5376) * KNN_TPB + threadIdx.x;
    if (t < 2048) { int r = t / 32, c = t % 32; o1[c * 64 + r] = d1[t]; return; }
    int t2 = t - 2048;
    if (t2 < 8192) { int r = t2 / 64, c = t2 % 64; o2[c * 128 + r] = d2[t2]; return; }
    int t3 = t2 - 8192;
    if (t3 < 32768) { int r = t3 / 128, c = t3 % 128; o3[c * 256 + r] = d3[t3]; return; }
    int t4 = t3 - 32768;
    if (t4 < 262144) { int r = t4 / 256, c = t4 % 256; o4[c * 1024 + r] = d4[t4]; return; }
    int t5 = t4 - 262144;
    if (t5 < 57344) pz[t5] = 0.f; // stage-1/2 BN bins (p1 + p2a + p2b)
}

// ---------------- LDS-tiled GEMM 64x64, BK=32 ----------------
// MODE 0: out = A@W + bias.  MODE 1: bnrelu(conv) + A@W (BN finalized in-kernel,
// parallel over 256 threads).  MODE 2: MODE 1 + per-batch column-max -> gbuf.
template <int MODE>
__global__ __launch_bounds__(TPB) void gemm64_kernel(const float* __restrict__ A, const float* __restrict__ W,
                                                     const float* __restrict__ bias,
                                                     const float* __restrict__ conv, const float* __restrict__ partial,
                                                     float* __restrict__ out, int M, int N, int K, int nsplit) {
    __shared__ float As[64][36];
    __shared__ float Bs[32][68];
    __shared__ float smean[64], sinv[64];
    int t = threadIdx.x;
    int tx = t & 15, ty = t >> 4;
    int colbase = blockIdx.x * 64, rowbase = blockIdx.y * 64;
    int r0 = ty * 4, c0 = tx * 4;
    if constexpr (MODE >= 1) {
        __shared__ double sred[2][4][64];
        int cc = t & 63, g = t >> 6;
        double s = 0.0, ss = 0.0;
        for (int sp = g; sp < nsplit; sp += 4) {
            s += partial[(size_t)sp * 2 * N + colbase + cc];
            ss += partial[(size_t)sp * 2 * N + N + colbase + cc];
        }
        sred[0][g][cc] = s; sred[1][g][cc] = ss;
        __syncthreads();
        if (t < 64) {
            double S = sred[0][0][t] + sred[0][1][t] + sred[0][2][t] + sred[0][3][t];
            double SS = sred[1][0][t] + sred[1][1][t] + sred[1][2][t] + sred[1][3][t];
            double mean = S / M;
            double var = SS / M - mean * mean;
            if (var < 0) var = 0;
            smean[t] = (float)mean;
            sinv[t] = rsqrtf((float)var + 1e-5f);
        }
        __syncthreads();
    }
    float4 acc0, acc1, acc2, acc3;
    if (MODE == 0) {
        float4 bv = *(const float4*)(bias + colbase + c0);
        acc0 = bv; acc1 = bv; acc2 = bv; acc3 = bv;
    } else {
        acc0 = make_float4(0.f, 0.f, 0.f, 0.f); acc1 = acc0; acc2 = acc0; acc3 = acc0;
    }
    for (int kt = 0; kt < K; kt += 32) {
#pragma unroll
        for (int l = 0; l < 2; ++l) {
            int lin = t + l * 256;
            int ar = lin >> 3, ak = (lin & 7) << 2;
            *(float4*)&As[ar][ak] = *(const float4*)(A + (size_t)(rowbase + ar) * K + kt + ak);
            int br = lin >> 4, bn = (lin & 15) << 2;
            *(float4*)&Bs[br][bn] = *(const float4*)(W + (size_t)(kt + br) * N + colbase + bn);
        }
        __syncthreads();
#pragma unroll 4
        for (int k = 0; k < 32; ++k) {
            float4 bv = *(const float4*)&Bs[k][c0];
            float a0 = As[r0][k], a1 = As[r0 + 1][k], a2 = As[r0 + 2][k], a3 = As[r0 + 3][k];
            acc0.x += a0 * bv.x; acc0.y += a0 * bv.y; acc0.z += a0 * bv.z; acc0.w += a0 * bv.w;
            acc1.x += a1 * bv.x; acc1.y += a1 * bv.y; acc1.z += a1 * bv.z; acc1.w += a1 * bv.w;
            acc2.x += a2 * bv.x; acc2.y += a2 * bv.y; acc2.z += a2 * bv.z; acc2.w += a2 * bv.w;
            acc3.x += a3 * bv.x; acc3.y += a3 * bv.y; acc3.z += a3 * bv.z; acc3.w += a3 * bv.w;
        }
        __syncthreads();
    }
    float4 accs[4] = {acc0, acc1, acc2, acc3};
    if constexpr (MODE >= 1) {
        float4 mean = *(const float4*)&smean[c0];
        float4 inv = *(const float4*)&sinv[c0];
#pragma unroll
        for (int rr = 0; rr < 4; ++rr) {
            float4 cv = *(const float4*)(conv + (size_t)(rowbase + r0 + rr) * N + colbase + c0);
            accs[rr].x += fmaxf((cv.x - mean.x) * inv.x, 0.f);
            accs[rr].y += fmaxf((cv.y - mean.y) * inv.y, 0.f);
            accs[rr].z += fmaxf((cv.z - mean.z) * inv.z, 0.f);
            accs[rr].w += fmaxf((cv.w - mean.w) * inv.w, 0.f);
        }
    }
    if constexpr (MODE == 2) {
        __shared__ float redmax[16][68];
        float4 tm;
        tm.x = fmaxf(fmaxf(accs[0].x, accs[1].x), fmaxf(accs[2].x, accs[3].x));
        tm.y = fmaxf(fmaxf(accs[0].y, accs[1].y), fmaxf(accs[2].y, accs[3].y));
        tm.z = fmaxf(fmaxf(accs[0].z, accs[1].z), fmaxf(accs[2].z, accs[3].z));
        tm.w = fmaxf(fmaxf(accs[0].w, accs[1].w), fmaxf(accs[2].w, accs[3].w));
        *(float4*)&redmax[ty][c0] = tm;
        __syncthreads();
        if (t < 64) {
            float m = redmax[0][t];
#pragma unroll
            for (int g = 1; g < 16; ++g) m = fmaxf(m, redmax[g][t]);
            out[(size_t)blockIdx.y * N + colbase + t] = m;
        }
    } else {
#pragma unroll
        for (int rr = 0; rr < 4; ++rr)
            *(float4*)(out + (size_t)(rowbase + r0 + rr) * N + colbase + c0) = accs[rr];
    }
}

// ---------------- conv_layer: center + max_n(theta * support), 4 ch/thread ----------------
// FUSE: accumulate BN (sum, sumsq) per channel via LDS reduce + 64-bin global
// atomics (Cout <= 256, exact grids only).
template <bool FUSE>
__global__ __launch_bounds__(TPB) void conv_act_kernel(const float* __restrict__ ndir, const int* __restrict__ knn,
                                const float* __restrict__ fout, const float* __restrict__ dir,
                                float* __restrict__ out, int B, int Vst, int K, int Cout,
                                float* __restrict__ bnpart) {
    __shared__ float sAcc[2][256];
    int t = blockIdx.x * blockDim.x + threadIdx.x;
    int nc4 = Cout >> 2;
    bool active = t < B * Vst * nc4;
    float4 o = make_float4(0.f, 0.f, 0.f, 0.f);
    int c4 = 0;
    if (active) {
        int row = t / nc4; c4 = (t % nc4) * 4;
        int b = row / Vst;
        float4 D0 = *(const float4*)(dir + c4);
        float4 D1 = *(const float4*)(dir + Cout + c4);
        float4 D2 = *(const float4*)(dir + 2 * Cout + c4);
        float4 e0, e1, e2;
        {
            float i0 = 1.f / fmaxf(sqrtf(D0.x * D0.x + D1.x * D1.x + D2.x * D2.x), 1e-12f);
            float i1 = 1.f / fmaxf(sqrtf(D0.y * D0.y + D1.y * D1.y + D2.y * D2.y), 1e-12f);
            float i2 = 1.f / fmaxf(sqrtf(D0.z * D0.z + D1.z * D1.z + D2.z * D2.z), 1e-12f);
            float i3 = 1.f / fmaxf(sqrtf(D0.w * D0.w + D1.w * D1.w + D2.w * D2.w), 1e-12f);
            e0 = make_float4(D0.x * i0, D0.y * i1, D0.z * i2, D0.w * i3);
            e1 = make_float4(D1.x * i0, D1.y * i1, D1.z * i2, D1.w * i3);
            e2 = make_float4(D2.x * i0, D2.y * i1, D2.z * i2, D2.w * i3);
        }
        int Cw = 2 * Cout;
        float4 m = make_float4(-FINF, -FINF, -FINF, -FINF);
        const float* nd = ndir + (size_t)row * K * 3;
        const int* kr = knn + (size_t)row * K;
        for (int n = 0; n < K; ++n) {
            int j = kr[n];
            float n0 = nd[n * 3], n1 = nd[n * 3 + 1], n2 = nd[n * 3 + 2];
            float4 s = *(const float4*)(fout + ((size_t)(b * Vst + j)) * Cw + Cout + c4);
            float t0 = fmaxf(n0 * e0.x + n1 * e1.x + n2 * e2.x, 0.f);
            float t1 = fmaxf(n0 * e0.y + n1 * e1.y + n2 * e2.y, 0.f);
            float t2 = fmaxf(n0 * e0.z + n1 * e1.z + n2 * e2.z, 0.f);
            float t3 = fmaxf(n0 * e0.w + n1 * e1.w + n2 * e2.w, 0.f);
            m.x = fmaxf(m.x, t0 * s.x);
            m.y = fmaxf(m.y, t1 * s.y);
            m.z = fmaxf(m.z, t2 * s.z);
            m.w = fmaxf(m.w, t3 * s.w);
        }
        float4 ctr = *(const float4*)(fout + (size_t)row * Cw + c4);
        o = make_float4(ctr.x + m.x, ctr.y + m.y, ctr.z + m.z, ctr.w + m.w);
        *(float4*)(out + (size_t)row * Cout + c4) = o;
    }
    if constexpr (FUSE) {
        for (int i = threadIdx.x; i < 2 * Cout; i += TPB) ((float*)sAcc)[i < Cout ? i : 256 + (i - Cout)] = 0.f;
        __syncthreads();
        if (active) {
            atomicAdd(&sAcc[0][c4 + 0], o.x); atomicAdd(&sAcc[1][c4 + 0], o.x * o.x);
            atomicAdd(&sAcc[0][c4 + 1], o.y); atomicAdd(&sAcc[1][c4 + 1], o.y * o.y);
            atomicAdd(&sAcc[0][c4 + 2], o.z); atomicAdd(&sAcc[1][c4 + 2], o.z * o.z);
            atomicAdd(&sAcc[0][c4 + 3], o.w); atomicAdd(&sAcc[1][c4 + 3], o.w * o.w);
        }
        __syncthreads();
        int bin = blockIdx.x & 63;
        for (int i = threadIdx.x; i < Cout; i += TPB) {
            atomicAdd(&bnpart[(size_t)bin * 2 * Cout + i], sAcc[0][i]);
            atomicAdd(&bnpart[(size_t)bin * 2 * Cout + Cout + i], sAcc[1][i]);
        }
    }
}

// ---------------- stage-3 FUSED: c4 GEMM (center+support) + conv_act + BN partials ----------------
__global__ __launch_bounds__(TPB) void s3_fused_kernel(const float* __restrict__ A, const float* __restrict__ W,
                                                       const float* __restrict__ bias,
                                                       const float* __restrict__ ndir, const int* __restrict__ knn,
                                                       const float* __restrict__ dir,
                                                       float* __restrict__ convp, float* __restrict__ bnpart) {
    constexpr int K = 256, N = 2048, Cout = 1024, KN = 20;
    __shared__ float As[64][36];
    __shared__ float Bc[32][68];
    __shared__ float Bsup[32][68];
    __shared__ float S[64][68];
    __shared__ float red[2][16][68];
    int t = threadIdx.x;
    int tx = t & 15, ty = t >> 4;
    int r0 = ty * 4, c0 = tx * 4;
    int batch = blockIdx.y;
    int colbase = blockIdx.x * 64;
    int rowbase = batch * 64;
    float4 accC[4], accS[4];
    {
        float4 bc = *(const float4*)(bias + colbase + c0);
        float4 bs = *(const float4*)(bias + Cout + colbase + c0);
#pragma unroll
        for (int rr = 0; rr < 4; ++rr) { accC[rr] = bc; accS[rr] = bs; }
    }
    for (int kt = 0; kt < K; kt += 32) {
#pragma unroll
        for (int l = 0; l < 2; ++l) {
            int lin = t + l * 256;
            int ar = lin >> 3, ak = (lin & 7) << 2;
            *(float4*)&As[ar][ak] = *(const float4*)(A + (size_t)(rowbase + ar) * K + kt + ak);
            int br = lin >> 4, bn = (lin & 15) << 2;
            *(float4*)&Bc[br][bn] = *(const float4*)(W + (size_t)(kt + br) * N + colbase + bn);
            *(float4*)&Bsup[br][bn] = *(const float4*)(W + (size_t)(kt + br) * N + Cout + colbase + bn);
        }
        __syncthreads();
#pragma unroll 4
        for (int k = 0; k < 32; ++k) {
            float4 bc = *(const float4*)&Bc[k][c0];
            float4 bs = *(const float4*)&Bsup[k][c0];
            float a0 = As[r0][k], a1 = As[r0 + 1][k], a2 = As[r0 + 2][k], a3 = As[r0 + 3][k];
            accC[0].x += a0 * bc.x; accC[0].y += a0 * bc.y; accC[0].z += a0 * bc.z; accC[0].w += a0 * bc.w;
            accC[1].x += a1 * bc.x; accC[1].y += a1 * bc.y; accC[1].z += a1 * bc.z; accC[1].w += a1 * bc.w;
            accC[2].x += a2 * bc.x; accC[2].y += a2 * bc.y; accC[2].z += a2 * bc.z; accC[2].w += a2 * bc.w;
            accC[3].x += a3 * bc.x; accC[3].y += a3 * bc.y; accC[3].z += a3 * bc.z; accC[3].w += a3 * bc.w;
            accS[0].x += a0 * bs.x; accS[0].y += a0 * bs.y; accS[0].z += a0 * bs.z; accS[0].w += a0 * bs.w;
            accS[1].x += a1 * bs.x; accS[1].y += a1 * bs.y; accS[1].z += a1 * bs.z; accS[1].w += a1 * bs.w;
            accS[2].x += a2 * bs.x; accS[2].y += a2 * bs.y; accS[2].z += a2 * bs.z; accS[2].w += a2 * bs.w;
            accS[3].x += a3 * bs.x; accS[3].y += a3 * bs.y; accS[3].z += a3 * bs.z; accS[3].w += a3 * bs.w;
        }
        __syncthreads();
    }
#pragma unroll
    for (int rr = 0; rr < 4; ++rr)
        *(float4*)&S[r0 + rr][c0] = accS[rr];
    __syncthreads();
    int c = colbase + c0;
    float4 D0 = *(const float4*)(dir + c);
    float4 D1 = *(const float4*)(dir + Cout + c);
    float4 D2 = *(const float4*)(dir + 2 * Cout + c);
    float4 e0, e1, e2;
    {
        float i0 = 1.f / fmaxf(sqrtf(D0.x * D0.x + D1.x * D1.x + D2.x * D2.x), 1e-12f);
        float i1 = 1.f / fmaxf(sqrtf(D0.y * D0.y + D1.y * D1.y + D2.y * D2.y), 1e-12f);
        float i2 = 1.f / fmaxf(sqrtf(D0.z * D0.z + D1.z * D1.z + D2.z * D2.z), 1e-12f);
        float i3 = 1.f / fmaxf(sqrtf(D0.w * D0.w + D1.w * D1.w + D2.w * D2.w), 1e-12f);
        e0 = make_float4(D0.x * i0, D0.y * i1, D0.z * i2, D0.w * i3);
        e1 = make_float4(D1.x * i0, D1.y * i1, D1.z * i2, D1.w * i3);
        e2 = make_float4(D2.x * i0, D2.y * i1, D2.z * i2, D2.w * i3);
    }
    float4 sum = make_float4(0.f, 0.f, 0.f, 0.f);
    float4 ssum = make_float4(0.f, 0.f, 0.f, 0.f);
#pragma unroll
    for (int rr = 0; rr < 4; ++rr) {
        int row = rowbase + r0 + rr;
        float4 m = make_float4(-FINF, -FINF, -FINF, -FINF);
        const float* nd = ndir + (size_t)row * KN * 3;
        const int* kr = knn + (size_t)row * KN;
        for (int n = 0; n < KN; ++n) {
            int j = kr[n];
            float n0 = nd[n * 3], n1 = nd[n * 3 + 1], n2 = nd[n * 3 + 2];
            float4 s = *(const float4*)&S[j][c0];
            float t0 = fmaxf(n0 * e0.x + n1 * e1.x + n2 * e2.x, 0.f);
            float t1 = fmaxf(n0 * e0.y + n1 * e1.y + n2 * e2.y, 0.f);
            float t2 = fmaxf(n0 * e0.z + n1 * e1.z + n2 * e2.z, 0.f);
            float t3 = fmaxf(n0 * e0.w + n1 * e1.w + n2 * e2.w, 0.f);
            m.x = fmaxf(m.x, t0 * s.x);
            m.y = fmaxf(m.y, t1 * s.y);
            m.z = fmaxf(m.z, t2 * s.z);
            m.w = fmaxf(m.w, t3 * s.w);
        }
        float4 o = make_float4(accC[rr].x + m.x, accC[rr].y + m.y, accC[rr].z + m.z, accC[rr].w + m.w);
        *(float4*)(convp + (size_t)row * Cout + colbase + c0) = o;
        sum.x += o.x; sum.y += o.y; sum.z += o.z; sum.w += o.w;
        ssum.x += o.x * o.x; ssum.y += o.y * o.y; ssum.z += o.z * o.z; ssum.w += o.w * o.w;
    }
    *(float4*)&red[0][ty][c0] = sum;
    *(float4*)&red[1][ty][c0] = ssum;
    __syncthreads();
    if (t < 64) {
        float Ssum = 0.f, SSsum = 0.f;
#pragma unroll
        for (int g = 0; g < 16; ++g) { Ssum += red[0][g][t]; SSsum += red[1][g][t]; }
        bnpart[(size_t)batch * 2048 + colbase + t] = Ssum;
        bnpart[(size_t)batch * 2048 + 1024 + colbase + t] = SSsum;
    }
}

// ---------------- pool: max over 4 NN features ----------------
__global__ __launch_bounds__(TPB) void pool_max_kernel(const float* __restrict__ fm, const int* __restrict__ knn4,
                                float* __restrict__ out, int B, int Vin, int pn, int C) {
    int t = blockIdx.x * blockDim.x + threadIdx.x;
    if (t >= B * pn * C) return;
    int row = t / C, c = t % C;
    int b = row / pn;
    const int* kr = knn4 + (size_t)row * 4;
    float m = fmaxf(fmaxf(fm[((size_t)(b * Vin + kr[0])) * C + c], fm[((size_t)(b * Vin + kr[1])) * C + c]),
                    fmaxf(fm[((size_t)(b * Vin + kr[2])) * C + c], fm[((size_t)(b * Vin + kr[3])) * C + c]));
    out[t] = m;
}

// ---------------- wave-per-output: out[r,c] = in[r,:]@w[c,:] + bias[c] ----------------
__global__ __launch_bounds__(TPB, 1) void gemm_t_wave_kernel(const float* __restrict__ in, const float* __restrict__ w,
                                   const float* __restrict__ bias, float* __restrict__ out,
                                   int rows, int Cin, int Cout) {
    int wid = (blockIdx.x * blockDim.x + threadIdx.x) >> 6;
    int lane = threadIdx.x & 63;
    if (wid >= rows * Cout) return;
    int r = wid / Cout, c = wid % Cout;
    const float4* a = (const float4*)(in + (size_t)r * Cin);
    const float4* wr = (const float4*)(w + (size_t)c * Cin);
    int n4 = Cin >> 2;
    float acc = 0.f;
    for (int k = lane; k < n4; k += 64) {
        float4 av = a[k], wv = wr[k];
        acc += av.x * wv.x + av.y * wv.y + av.z * wv.z + av.w * wv.w;
    }
#pragma unroll
    for (int off = 32; off > 0; off >>= 1) acc += __shfl_xor(acc, off, 64);
    if (lane == 0) out[wid] = acc + bias[c];
}

// ---------------- fused classifier tail ----------------
__global__ __launch_bounds__(TPB, 1) void cls_fused_kernel(const float* __restrict__ h,
                                 const float* __restrict__ gam, const float* __restrict__ beta,
                                 const float* __restrict__ w2, const float* __restrict__ b2,
                                 float* __restrict__ out) {
    __shared__ float smean[256], sa[256];
    int t = threadIdx.x;
    {
        float s = 0.f, ss = 0.f;
        for (int b = 0; b < 32; ++b) {
            float v = h[(size_t)b * 256 + t];
            s += v; ss += v * v;
        }
        float mn = s / 32.f;
        float var = ss / 32.f - mn * mn;
        if (var < 0.f) var = 0.f;
        smean[t] = mn;
        sa[t] = rsqrtf(var + 1e-5f) * gam[t];
    }
    __syncthreads();
    int wid = blockIdx.x * 4 + (t >> 6);
    int lane = t & 63;
    if (wid >= 32 * 40) return;
    int b = wid / 40, o = wid % 40;
    float acc = 0.f;
#pragma unroll
    for (int kk = 0; kk < 4; ++kk) {
        int c = lane + kk * 64;
        float v = fmaxf((h[b * 256 + c] - smean[c]) * sa[c] + beta[c], 0.f);
        acc += v * w2[o * 256 + c];
    }
#pragma unroll
    for (int off = 32; off > 0; off >>= 1) acc += __shfl_xor(acc, off, 64);
    if (lane == 0) out[wid] = acc + b2[o];
}

extern "C" void kernel_launch(void* const* d_in, const int* in_sizes, int n_in,
                              void* d_out, int out_size, void* d_ws, size_t ws_size,
                              hipStream_t stream) {
    const float* vertices = (const float*)d_in[0];
    const float* c0_dir = (const float*)d_in[1];
    const float* c1_w  = (const float*)d_in[2];
    const float* c1_b  = (const float*)d_in[3];
    const float* c1_dir = (const float*)d_in[4];
    const float* d1_w  = (const float*)d_in[5];
    const float* c2_w  = (const float*)d_in[6];
    const float* c2_b  = (const float*)d_in[7];
    const float* c2_dir = (const float*)d_in[8];
    const float* d2_w  = (const float*)d_in[9];
    const float* c3_w  = (const float*)d_in[10];
    const float* c3_b  = (const float*)d_in[11];
    const float* c3_dir = (const float*)d_in[12];
    const float* d3_w  = (const float*)d_in[13];
    const float* c4_w  = (const float*)d_in[14];
    const float* c4_b  = (const float*)d_in[15];
    const float* c4_dir = (const float*)d_in[16];
    const float* d4_w  = (const float*)d_in[17];
    const float* cls_w1 = (const float*)d_in[18];
    const float* cls_b1 = (const float*)d_in[19];
    const float* cls_g  = (const float*)d_in[20];
    const float* cls_beta = (const float*)d_in[21];
    const float* cls_w2 = (const float*)d_in[22];
    const float* cls_b2 = (const float*)d_in[23];

    const int B = 32;
    float* ws = (float*)d_ws;
    size_t off = 0;
    auto alloc = [&](size_t n) { float* p = ws + off; off += n; return p; };
    int*   knn1  = (int*)alloc(655360);     // B*1024*20
    int*   knn2  = (int*)alloc(163840);     // B*256*20
    int*   knn3  = (int*)alloc(40960);      // B*64*20
    int*   knn4_1 = (int*)alloc(32768);     // B*256*4
    int*   knn4_2 = (int*)alloc(8192);      // B*64*4
    float* ndir1 = alloc(1966080);          // B*1024*20*3
    float* ndir2 = alloc(491520);           // B*256*20*3
    float* ndir3 = alloc(122880);           // B*64*20*3
    float* fm0   = alloc(1048576);          // B*1024*32
    float* fm1   = alloc(2097152);          // B*1024*64
    float* fm1p  = alloc(524288);           // B*256*64
    float* fm2   = alloc(1048576);          // B*256*128
    float* fm3   = alloc(2097152);          // B*256*256
    float* fm3p  = alloc(524288);           // B*64*256
    float* fout  = alloc(4194304);          // stage-1/2 fout
    float* convp = alloc(2097152);          // pre-BN conv out
    float* gbuf  = alloc(32768);            // B*1024
    float* hbuf  = alloc(8192);             // B*256
    float* d1t   = alloc(2048);             // 32 x 64
    float* d2t   = alloc(8192);             // 64 x 128
    float* d3t   = alloc(32768);            // 128 x 256
    float* d4t   = alloc(262144);           // 256 x 1024
    float* pz    = alloc(57344);            // zeroed BN bins: p1(8K) + p2a(16K) + p2b(32K)
    float* p1    = pz;                      // 64 bins x 2 x 64
    float* p2a   = pz + 8192;               // 64 bins x 2 x 128
    float* p2b   = pz + 24576;              // 64 bins x 2 x 256
    float* p3    = alloc(65536);            // stage-3 partials: 32 bins x 2 x 1024 (plain stores)

    // ---- prep: all knn stages + transposes + BN-bin zeroing, one 1-D launch ----
    prep_kernel<<<6084, KNN_TPB, 0, stream>>>(
        vertices, c0_dir, knn1, ndir1, fm0, knn4_1, knn2, ndir2, knn4_2, knn3, ndir3,
        d1_w, d2_w, d3_w, d4_w, d1t, d2t, d3t, d4t, pz);

    // ---- stage 1 (V=1024) ----
    gemm64_kernel<0><<<dim3(2, 512), TPB, 0, stream>>>(fm0, c1_w, c1_b, nullptr, nullptr, fout, B * 1024, 128, 32, 0);
    conv_act_kernel<true><<<nblk((long)B * 1024 * 16), TPB, 0, stream>>>(ndir1, knn1, fout, c1_dir, convp, B, 1024, 20, 64, p1);
    gemm64_kernel<1><<<dim3(1, 512), TPB, 0, stream>>>(fm0, d1t, nullptr, convp, p1, fm1, B * 1024, 64, 32, 64);
    pool_max_kernel<<<nblk((long)B * 256 * 64), TPB, 0, stream>>>(fm1, knn4_1, fm1p, B, 1024, 256, 64);

    // ---- stage 2 (V=256) ----
    gemm64_kernel<0><<<dim3(4, 128), TPB, 0, stream>>>(fm1p, c2_w, c2_b, nullptr, nullptr, fout, B * 256, 256, 64, 0);
    conv_act_kernel<true><<<nblk((long)B * 256 * 32), TPB, 0, stream>>>(ndir2, knn2, fout, c2_dir, convp, B, 256, 20, 128, p2a);
    gemm64_kernel<1><<<dim3(2, 128), TPB, 0, stream>>>(fm1p, d2t, nullptr, convp, p2a, fm2, B * 256, 128, 64, 64);
    gemm64_kernel<0><<<dim3(8, 128), TPB, 0, stream>>>(fm2, c3_w, c3_b, nullptr, nullptr, fout, B * 256, 512, 128, 0);
    conv_act_kernel<true><<<nblk((long)B * 256 * 64), TPB, 0, stream>>>(ndir2, knn2, fout, c3_dir, convp, B, 256, 20, 256, p2b);
    gemm64_kernel<1><<<dim3(4, 128), TPB, 0, stream>>>(fm2, d3t, nullptr, convp, p2b, fm3, B * 256, 256, 128, 64);
    pool_max_kernel<<<nblk((long)B * 64 * 256), TPB, 0, stream>>>(fm3, knn4_2, fm3p, B, 256, 64, 256);

    // ---- stage 3 (V=64): fused c4 GEMM + conv_act + BN partials ----
    s3_fused_kernel<<<dim3(16, 32), TPB, 0, stream>>>(fm3p, c4_w, c4_b, ndir3, knn3, c4_dir, convp, p3);
    gemm64_kernel<2><<<dim3(16, 32), TPB, 0, stream>>>(fm3p, d4t, nullptr, convp, p3, gbuf, B * 64, 1024, 256, 32);

    // ---- classifier ----
    gemm_t_wave_kernel<<<nblk((long)32 * 256 * 64), TPB, 0, stream>>>(gbuf, cls_w1, cls_b1, hbuf, 32, 1024, 256);
    cls_fused_kernel<<<320, TPB, 0, stream>>>(hbuf, cls_g, cls_beta, cls_w2, cls_b2, (float*)d_out);
}